// Round 1
// baseline (6014.687 us; speedup 1.0000x reference)
//
#include <hip/hip_runtime.h>
#include <math.h>

// ---------------------------------------------------------------------------
// Problem constants (B=4, T=1024, C=1024, T2=257, H=16, hd=64)
// ---------------------------------------------------------------------------
#define BB   4
#define TT   1024
#define CC   1024
#define TT2  257
#define NH   16
#define HD   64

// ---------------------------------------------------------------------------
// LayerNorm: one block (256 thr) per row of length 1024, float4 vectorized
// ---------------------------------------------------------------------------
__global__ __launch_bounds__(256) void ln_kernel(
    const float* __restrict__ x, const float* __restrict__ g,
    const float* __restrict__ bt, float* __restrict__ out)
{
    int row = blockIdx.x;
    int tid = threadIdx.x;
    const float4 v = *(const float4*)(x + (size_t)row * CC + tid * 4);
    float s  = v.x + v.y + v.z + v.w;
    float ss = v.x * v.x + v.y * v.y + v.z * v.z + v.w * v.w;
#pragma unroll
    for (int off = 32; off >= 1; off >>= 1) {
        s  += __shfl_xor(s, off);
        ss += __shfl_xor(ss, off);
    }
    __shared__ float rs[4], rss[4];
    int wave = tid >> 6;
    if ((tid & 63) == 0) { rs[wave] = s; rss[wave] = ss; }
    __syncthreads();
    float S  = rs[0] + rs[1] + rs[2] + rs[3];
    float SS = rss[0] + rss[1] + rss[2] + rss[3];
    float mu   = S * (1.0f / CC);
    float var  = SS * (1.0f / CC) - mu * mu;
    float rstd = rsqrtf(var + 1e-5f);
    int c = tid * 4;
    float4 gg = *(const float4*)(g + c);
    float4 bb = *(const float4*)(bt + c);
    float4 r;
    r.x = (v.x - mu) * rstd * gg.x + bb.x;
    r.y = (v.y - mu) * rstd * gg.y + bb.y;
    r.z = (v.z - mu) * rstd * gg.z + bb.z;
    r.w = (v.w - mu) * rstd * gg.w + bb.w;
    *(float4*)(out + (size_t)row * CC + c) = r;
}

// ---------------------------------------------------------------------------
// GELU (tanh approx, matches jax.nn.gelu approximate=True)
// ---------------------------------------------------------------------------
__device__ __forceinline__ float gelu_tanh(float x)
{
    float x3 = x * x * x;
    return 0.5f * x * (1.0f + tanhf(0.7978845608028654f * (x + 0.044715f * x3)));
}

// ---------------------------------------------------------------------------
// Generic fp32 GEMM: out = act((A @ W) * scale + bias) + res
//   A [M,K] lda, row-major.
//   W: !TRANSB -> [K,N] ldw ; TRANSB -> [N,K] ldw (out[m][n] = sum_k A.W[n][k])
//   batched via blockIdx.z with element strides (0 strides => shared operand).
// 128x128 tile, BK=16, 256 threads, 8x8 micro-tile (2x2 blocks of 4x4).
// LDS layouts padded to 132 so wave accesses are <=2-way (free on gfx950).
// ---------------------------------------------------------------------------
template<bool TRANSB, bool GELU>
__global__ __launch_bounds__(256) void gemm_kernel(
    const float* __restrict__ A, const float* __restrict__ W,
    const float* __restrict__ bias, const float* __restrict__ res,
    float* __restrict__ out,
    int M, int N, int K, int lda, int ldw, int ldo,
    long long strideA, long long strideW, long long strideO,
    float scale)
{
    __shared__ float As[16][132];
    __shared__ float Bs[16][132];
    int zb = blockIdx.z;
    A += strideA * zb;
    W += strideW * zb;
    out += strideO * zb;
    if (res) res += strideO * zb;

    int tid = threadIdx.x;
    int tx = tid & 15, ty = tid >> 4;
    int r0 = blockIdx.y * 128, c0 = blockIdx.x * 128;

    float acc[8][8];
#pragma unroll
    for (int i = 0; i < 8; ++i)
#pragma unroll
        for (int j = 0; j < 8; ++j) acc[i][j] = 0.0f;

    for (int k0 = 0; k0 < K; k0 += 16) {
        // stage A tile (transposed into As[k][m])
#pragma unroll
        for (int ii = 0; ii < 8; ++ii) {
            int l = ii * 256 + tid;
            int r = l >> 4, kk = l & 15;
            int gr = r0 + r, gk = k0 + kk;
            float v = 0.0f;
            if (gr < M && gk < K) v = A[(long long)gr * lda + gk];
            As[kk][r] = v;
        }
        // stage B tile into Bs[k][n]
#pragma unroll
        for (int ii = 0; ii < 8; ++ii) {
            int l = ii * 256 + tid;
            if (!TRANSB) {
                int kk = l >> 7, n = l & 127;
                int gk = k0 + kk, gn = c0 + n;
                float v = 0.0f;
                if (gk < K && gn < N) v = W[(long long)gk * ldw + gn];
                Bs[kk][n] = v;
            } else {
                int n = l >> 4, kk = l & 15;
                int gn = c0 + n, gk = k0 + kk;
                float v = 0.0f;
                if (gn < N && gk < K) v = W[(long long)gn * ldw + gk];
                Bs[kk][n] = v;
            }
        }
        __syncthreads();
#pragma unroll
        for (int kk = 0; kk < 16; ++kk) {
            float a[8], b[8];
            *(float4*)&a[0] = *(const float4*)&As[kk][ty * 4];
            *(float4*)&a[4] = *(const float4*)&As[kk][64 + ty * 4];
            *(float4*)&b[0] = *(const float4*)&Bs[kk][tx * 4];
            *(float4*)&b[4] = *(const float4*)&Bs[kk][64 + tx * 4];
#pragma unroll
            for (int i = 0; i < 8; ++i)
#pragma unroll
                for (int j = 0; j < 8; ++j) acc[i][j] += a[i] * b[j];
        }
        __syncthreads();
    }

    // epilogue
#pragma unroll
    for (int i = 0; i < 8; ++i) {
        int rr = (i < 4) ? (ty * 4 + i) : (64 + ty * 4 + (i - 4));
        int gr = r0 + rr;
        if (gr >= M) continue;
#pragma unroll
        for (int jg = 0; jg < 2; ++jg) {
            int gc = c0 + jg * 64 + tx * 4;
            if (gc >= N) continue;
            float vv[4];
#pragma unroll
            for (int j = 0; j < 4; ++j) vv[j] = acc[i][jg * 4 + j] * scale;
            if ((gc + 3 < N) && ((ldo & 3) == 0)) {
                long long off = (long long)gr * ldo + gc;
                if (bias) {
                    float4 bv = *(const float4*)(bias + gc);
                    vv[0] += bv.x; vv[1] += bv.y; vv[2] += bv.z; vv[3] += bv.w;
                }
                if (GELU) {
#pragma unroll
                    for (int j = 0; j < 4; ++j) vv[j] = gelu_tanh(vv[j]);
                }
                if (res) {
                    float4 rv = *(const float4*)(res + off);
                    vv[0] += rv.x; vv[1] += rv.y; vv[2] += rv.z; vv[3] += rv.w;
                }
                float4 o4 = make_float4(vv[0], vv[1], vv[2], vv[3]);
                *(float4*)(out + off) = o4;
            } else {
#pragma unroll
                for (int j = 0; j < 4; ++j) {
                    int gcj = gc + j;
                    if (gcj >= N) break;
                    float v = vv[j];
                    if (bias) v += bias[gcj];
                    if (GELU) v = gelu_tanh(v);
                    long long off = (long long)gr * ldo + gcj;
                    if (res) v += res[off];
                    out[off] = v;
                }
            }
        }
    }
}

// ---------------------------------------------------------------------------
// Flash-style causal self-attention over qkv buffer [B*T, 3C].
//   q cols [0,1024), k cols [1024,2048), v cols [2048,3072); head h owns 64.
// Block: 256 thr = 64 q-rows x 4 "quads". Grid: (T/64, B*H).
// Online softmax; O accumulated in registers (16 dims per thread).
// ---------------------------------------------------------------------------
__global__ __launch_bounds__(256) void flash_attn_kernel(
    const float* __restrict__ qkv, float* __restrict__ out)
{
    __shared__ float Qs[64][65];
    __shared__ float Ks[64][65];
    __shared__ float Vs[64][65];
    __shared__ float Ps[64][65];

    int b  = blockIdx.y >> 4;   // / NH
    int h  = blockIdx.y & 15;   // % NH
    int qt = blockIdx.x;
    int qi0 = qt * 64;
    int tid = threadIdx.x;
    int i    = tid >> 2;        // q-row within tile (0..63)
    int quad = tid & 3;
    int d0   = quad * 16;

    const size_t rowBase = (size_t)(b * TT) * (3 * CC);

    // load Q tile
    {
        const float* src = qkv + rowBase + (size_t)(qi0 + i) * (3 * CC) + h * HD + d0;
#pragma unroll
        for (int j = 0; j < 4; ++j)
            *(float4*)&Qs[i][d0 + 4 * j] = *(const float4*)&src[4 * j];
    }

    float m = -INFINITY, l = 0.0f;
    float o[16];
#pragma unroll
    for (int d = 0; d < 16; ++d) o[d] = 0.0f;

    for (int kt = 0; kt <= qt; ++kt) {
        // load K,V tiles
        {
            const float* kp = qkv + rowBase + (size_t)(kt * 64 + i) * (3 * CC) + CC + h * HD + d0;
            const float* vp = kp + CC;
#pragma unroll
            for (int j = 0; j < 4; ++j) {
                *(float4*)&Ks[i][d0 + 4 * j] = *(const float4*)&kp[4 * j];
                *(float4*)&Vs[i][d0 + 4 * j] = *(const float4*)&vp[4 * j];
            }
        }
        __syncthreads();

        // phase A: scores for (row i, cols d0..d0+15)
        float s[16];
#pragma unroll
        for (int jj = 0; jj < 16; ++jj) s[jj] = 0.0f;
#pragma unroll
        for (int d4 = 0; d4 < 16; ++d4) {
            float4 qv = *(const float4*)&Qs[i][d4 * 4];
#pragma unroll
            for (int jj = 0; jj < 16; ++jj) {
                float4 kv = *(const float4*)&Ks[d0 + jj][d4 * 4];
                s[jj] += qv.x * kv.x + qv.y * kv.y + qv.z * kv.z + qv.w * kv.w;
            }
        }
        int qglob = qi0 + i;
        float tmax = -INFINITY;
#pragma unroll
        for (int jj = 0; jj < 16; ++jj) {
            int kglob = kt * 64 + d0 + jj;
            s[jj] = (kglob <= qglob) ? s[jj] * 0.125f : -INFINITY;
            tmax = fmaxf(tmax, s[jj]);
        }
        tmax = fmaxf(tmax, __shfl_xor(tmax, 1));
        tmax = fmaxf(tmax, __shfl_xor(tmax, 2));
        float mnew = fmaxf(m, tmax);
        float tl = 0.0f;
#pragma unroll
        for (int jj = 0; jj < 16; ++jj) {
            float p = expf(s[jj] - mnew);   // expf(-inf - finite) = 0 handles mask
            Ps[i][d0 + jj] = p;
            tl += p;
        }
        tl += __shfl_xor(tl, 1);
        tl += __shfl_xor(tl, 2);
        float alpha = expf(m - mnew);       // first tile: expf(-inf) = 0
        l = l * alpha + tl;
        m = mnew;
        __syncthreads();

        // phase B: O[i][d0..d0+15] update
#pragma unroll
        for (int d = 0; d < 16; ++d) o[d] *= alpha;
        for (int j = 0; j < 64; ++j) {
            float p = Ps[i][j];
            float4 v0 = *(const float4*)&Vs[j][d0];
            float4 v1 = *(const float4*)&Vs[j][d0 + 4];
            float4 v2 = *(const float4*)&Vs[j][d0 + 8];
            float4 v3 = *(const float4*)&Vs[j][d0 + 12];
            o[0]  += p * v0.x; o[1]  += p * v0.y; o[2]  += p * v0.z; o[3]  += p * v0.w;
            o[4]  += p * v1.x; o[5]  += p * v1.y; o[6]  += p * v1.z; o[7]  += p * v1.w;
            o[8]  += p * v2.x; o[9]  += p * v2.y; o[10] += p * v2.z; o[11] += p * v2.w;
            o[12] += p * v3.x; o[13] += p * v3.y; o[14] += p * v3.z; o[15] += p * v3.w;
        }
        __syncthreads();
    }

    float inv = 1.0f / l;
    float* op = out + (size_t)(b * TT + qi0 + i) * CC + h * HD + d0;
#pragma unroll
    for (int g = 0; g < 4; ++g) {
        float4 r = make_float4(o[g * 4] * inv, o[g * 4 + 1] * inv,
                               o[g * 4 + 2] * inv, o[g * 4 + 3] * inv);
        *(float4*)(op + g * 4) = r;
    }
}

// ---------------------------------------------------------------------------
// Row softmax over length-257 rows (cross-attn scores), in place.
// ---------------------------------------------------------------------------
__global__ __launch_bounds__(256) void softmax257_kernel(float* __restrict__ att)
{
    int row = blockIdx.x;
    float* p = att + (size_t)row * TT2;
    int tid = threadIdx.x;
    float v0 = p[tid];
    float v1 = (tid == 0) ? p[256] : -INFINITY;
    float m = fmaxf(v0, v1);
#pragma unroll
    for (int off = 32; off >= 1; off >>= 1) m = fmaxf(m, __shfl_xor(m, off));
    __shared__ float red[8];
    int wave = tid >> 6;
    if ((tid & 63) == 0) red[wave] = m;
    __syncthreads();
    m = fmaxf(fmaxf(red[0], red[1]), fmaxf(red[2], red[3]));
    float e0 = expf(v0 - m);
    float e1 = (tid == 0) ? expf(v1 - m) : 0.0f;
    float s = e0 + e1;
#pragma unroll
    for (int off = 32; off >= 1; off >>= 1) s += __shfl_xor(s, off);
    if ((tid & 63) == 0) red[4 + wave] = s;
    __syncthreads();
    s = red[4] + red[5] + red[6] + red[7];
    float inv = 1.0f / s;
    p[tid] = e0 * inv;
    if (tid == 0) p[256] = e1 * inv;
}

// ---------------------------------------------------------------------------
// float4 copy
// ---------------------------------------------------------------------------
__global__ __launch_bounds__(256) void copy4_kernel(
    const float4* __restrict__ src, float4* __restrict__ dst, int n4)
{
    int i = blockIdx.x * blockDim.x + threadIdx.x;
    if (i < n4) dst[i] = src[i];
}

// ---------------------------------------------------------------------------
// Host-side launch helper for GEMM
// ---------------------------------------------------------------------------
static inline void launch_gemm(bool transB, bool gelu,
    const float* A, const float* W, const float* bias, const float* res,
    float* out, int M, int N, int K, int lda, int ldw, int ldo,
    int batch, long long sA, long long sW, long long sO, float scale,
    hipStream_t stream)
{
    dim3 grid((N + 127) / 128, (M + 127) / 128, batch);
    dim3 block(256);
    if (transB)
        gemm_kernel<true, false><<<grid, block, 0, stream>>>(
            A, W, bias, res, out, M, N, K, lda, ldw, ldo, sA, sW, sO, scale);
    else if (gelu)
        gemm_kernel<false, true><<<grid, block, 0, stream>>>(
            A, W, bias, res, out, M, N, K, lda, ldw, ldo, sA, sW, sO, scale);
    else
        gemm_kernel<false, false><<<grid, block, 0, stream>>>(
            A, W, bias, res, out, M, N, K, lda, ldw, ldo, sA, sW, sO, scale);
}

extern "C" void kernel_launch(void* const* d_in, const int* in_sizes, int n_in,
                              void* d_out, int out_size, void* d_ws, size_t ws_size,
                              hipStream_t stream)
{
    // inputs (setup_inputs dict order)
    const float* text_emb    = (const float*)d_in[0];   // [4,1024,1024]
    const float* img_emb     = (const float*)d_in[1];   // [4,257,1024]
    const float* ln1_g       = (const float*)d_in[2];
    const float* ln1_b       = (const float*)d_in[3];
    const float* ln2_g       = (const float*)d_in[4];
    const float* ln2_b       = (const float*)d_in[5];
    const float* ln3_g       = (const float*)d_in[6];
    const float* ln3_b       = (const float*)d_in[7];
    const float* qkv_w       = (const float*)d_in[8];   // [1024,3072]
    const float* qkv_b       = (const float*)d_in[9];
    const float* attn_proj_w = (const float*)d_in[10];  // [1024,1024]
    const float* attn_proj_b = (const float*)d_in[11];
    const float* ca_q_w      = (const float*)d_in[12];
    const float* ca_q_b      = (const float*)d_in[13];
    const float* ca_kv_w     = (const float*)d_in[14];  // [1024,2048]
    const float* ca_kv_b     = (const float*)d_in[15];
    const float* ca_proj_w   = (const float*)d_in[16];
    const float* ca_proj_b   = (const float*)d_in[17];
    const float* mlp_fc_w    = (const float*)d_in[18];  // [1024,4096]
    const float* mlp_fc_b    = (const float*)d_in[19];
    const float* mlp_proj_w  = (const float*)d_in[20];  // [4096,1024]
    const float* mlp_proj_b  = (const float*)d_in[21];

    const int M1 = BB * TT;        // 4096
    const int Mkv = BB * TT2;      // 1028

    // workspace carve-up (floats). Total = 28,323,328 fl = ~113 MB.
    float* ws       = (float*)d_ws;
    float* buf_big  = ws;                       // 16,777,216 (qkv 4096x3072 / h 4096x4096)
    float* buf_ln   = buf_big + 16777216;       //  4,194,304
    float* buf_attn = buf_ln + 4194304;         //  4,194,304
    float* buf_kv   = buf_attn + 4194304;       //  2,105,344 (1028 x 2048)
    float* buf_att  = buf_kv + 2105344;         //  1,052,672 (4 x 1024 x 257)

    float* out_x   = (float*)d_out;             // [4,1024,1024]
    float* out_img = out_x + (size_t)M1 * CC;   // [4,257,1024]

    // 1. ln1(text_emb) -> buf_ln
    ln_kernel<<<dim3(M1), dim3(256), 0, stream>>>(text_emb, ln1_g, ln1_b, buf_ln);

    // 2. qkv = ln1 @ qkv_w + b  -> buf_big [4096,3072]
    launch_gemm(false, false, buf_ln, qkv_w, qkv_b, nullptr, buf_big,
                M1, 3 * CC, CC, CC, 3 * CC, 3 * CC, 1, 0, 0, 0, 1.0f, stream);

    // 3. causal self-attention -> buf_attn [4096,1024]
    flash_attn_kernel<<<dim3(TT / 64, BB * NH), dim3(256), 0, stream>>>(buf_big, buf_attn);

    // 4. x = text_emb + attn @ proj_w + b  -> out_x
    launch_gemm(false, false, buf_attn, attn_proj_w, attn_proj_b, text_emb, out_x,
                M1, CC, CC, CC, CC, CC, 1, 0, 0, 0, 1.0f, stream);

    // 5. ln3(x) -> buf_ln
    ln_kernel<<<dim3(M1), dim3(256), 0, stream>>>(out_x, ln3_g, ln3_b, buf_ln);

    // 6. q = ln3 @ ca_q_w + b -> buf_attn (reuse)
    launch_gemm(false, false, buf_ln, ca_q_w, ca_q_b, nullptr, buf_attn,
                M1, CC, CC, CC, CC, CC, 1, 0, 0, 0, 1.0f, stream);

    // 7. kv = img_emb @ ca_kv_w + b -> buf_kv [1028,2048]
    launch_gemm(false, false, img_emb, ca_kv_w, ca_kv_b, nullptr, buf_kv,
                Mkv, 2 * CC, CC, CC, 2 * CC, 2 * CC, 1, 0, 0, 0, 1.0f, stream);

    // 8. att = (q @ k^T) / sqrt(C)  (batched NT) -> buf_att [4,1024,257]
    launch_gemm(true, false, buf_attn, buf_kv, nullptr, nullptr, buf_att,
                TT, TT2, CC, CC, 2 * CC, TT2,
                BB, (long long)TT * CC, (long long)TT2 * 2 * CC, (long long)TT * TT2,
                0.03125f, stream);

    // 9. softmax rows
    softmax257_kernel<<<dim3(BB * TT), dim3(256), 0, stream>>>(buf_att);

    // 10. caout = att @ v  (batched NN, K=257) -> buf_ln (reuse)
    launch_gemm(false, false, buf_att, buf_kv + CC, nullptr, nullptr, buf_ln,
                TT, CC, TT2, TT2, 2 * CC, CC,
                BB, (long long)TT * TT2, (long long)TT2 * 2 * CC, (long long)TT * CC,
                1.0f, stream);

    // 11. x += caout @ ca_proj_w + b  (in-place residual on out_x)
    launch_gemm(false, false, buf_ln, ca_proj_w, ca_proj_b, out_x, out_x,
                M1, CC, CC, CC, CC, CC, 1, 0, 0, 0, 1.0f, stream);

    // 12. ln2(x) -> buf_attn (reuse)
    ln_kernel<<<dim3(M1), dim3(256), 0, stream>>>(out_x, ln2_g, ln2_b, buf_attn);

    // 13. h = gelu(ln2 @ fc_w + b) -> buf_big [4096,4096]
    launch_gemm(false, true, buf_attn, mlp_fc_w, mlp_fc_b, nullptr, buf_big,
                M1, 4 * CC, CC, CC, 4 * CC, 4 * CC, 1, 0, 0, 0, 1.0f, stream);

    // 14. x += h @ mlp_proj_w + b
    launch_gemm(false, false, buf_big, mlp_proj_w, mlp_proj_b, out_x, out_x,
                M1, CC, 4 * CC, 4 * CC, CC, CC, 1, 0, 0, 0, 1.0f, stream);

    // 15. out_img = img_emb
    {
        int n4 = (BB * TT2 * CC) / 4;   // 263,168
        copy4_kernel<<<dim3((n4 + 255) / 256), dim3(256), 0, stream>>>(
            (const float4*)img_emb, (float4*)out_img, n4);
    }
}

// Round 2
// 1803.195 us; speedup vs baseline: 3.3356x; 3.3356x over previous
//
#include <hip/hip_runtime.h>
#include <math.h>

// Problem constants (B=4, T=1024, C=1024, T2=257, H=16, hd=64)
#define BB   4
#define TT   1024
#define CC   1024
#define TT2  257
#define NH   16
#define HD   64
typedef long long ll;

typedef __attribute__((ext_vector_type(8))) short short8;   // 8 bf16 (4 VGPR)
typedef __attribute__((ext_vector_type(4))) float f32x4;    // MFMA acc

// ---------------------------------------------------------------------------
// bf16 helpers: round-to-nearest-even convert + hi/lo split (fp32 ~= hi+lo)
// ---------------------------------------------------------------------------
__device__ __forceinline__ ushort f2bf(float f) {
    unsigned u = __float_as_uint(f);
    u += 0x7fffu + ((u >> 16) & 1u);
    return (ushort)(u >> 16);
}
__device__ __forceinline__ float bf2f(ushort h) {
    return __uint_as_float(((unsigned)h) << 16);
}
__device__ __forceinline__ void split2(float v, ushort& h, ushort& l) {
    h = f2bf(v);
    l = f2bf(v - bf2f(h));
}

__device__ __forceinline__ void async_cp16(const ushort* g, ushort* l) {
    __builtin_amdgcn_global_load_lds(
        (__attribute__((address_space(1))) void*)g,
        (__attribute__((address_space(3))) void*)l, 16, 0, 0);
}

__device__ __forceinline__ float gelu_tanh(float x) {
    float x3 = x * x * x;
    return 0.5f * x * (1.0f + tanhf(0.7978845608028654f * (x + 0.044715f * x3)));
}

// ---------------------------------------------------------------------------
// Split-bf16 MFMA GEMM.  out = act((A@B^T)*scale + bias) [+ res]
//   A planes: AH/AL [M][lda] bf16 (hi/lo of fp32 A)
//   B planes: BH/BL [N][ldb] bf16 (hi/lo of B^T, i.e. row n holds B column n)
//   128x128 tile, BK=32, 4 waves, per-wave 64x64 (4x4 frags of 16x16x32).
//   Product: hi*hi + lo*hi + hi*lo (lo*lo dropped) ~= fp32 GEMM.
//   Staging: global_load_lds dwordx4, linear LDS [128][32] bf16 per plane.
//   K must be a multiple of 32 (buffers K-padded with zeros where needed).
//   M/N partial tiles: staging reads padded allocations; epilogue guards.
// ---------------------------------------------------------------------------
template<bool GELU, bool SPLIT>
__global__ __launch_bounds__(256, 2) void gemm_sp(
    const ushort* __restrict__ AH, const ushort* __restrict__ AL, int lda,
    const ushort* __restrict__ BH, const ushort* __restrict__ BL, int ldb,
    const float* __restrict__ bias, const float* __restrict__ res,
    float* __restrict__ outF, ushort* __restrict__ outH, ushort* __restrict__ outL,
    int M, int N, int K, int ldo, float scale,
    ll sA, ll sB, ll sO)
{
    __shared__ __align__(16) ushort AsH[128 * 32];
    __shared__ __align__(16) ushort AsL[128 * 32];
    __shared__ __align__(16) ushort BsH[128 * 32];
    __shared__ __align__(16) ushort BsL[128 * 32];

    int z = blockIdx.z;
    AH += (size_t)sA * z; AL += (size_t)sA * z;
    BH += (size_t)sB * z; BL += (size_t)sB * z;

    int tid = threadIdx.x;
    int w = tid >> 6, lane = tid & 63;
    int g = lane >> 4, fr = lane & 15;
    int wr = w >> 1, wc = w & 1;
    int r0 = blockIdx.y * 128, c0 = blockIdx.x * 128;

    // each wave stages one LDS plane (8 x global_load_lds dwordx4 = 128 rows)
    const ushort* gb;
    int ld_;
    ushort* lb;
    if (w == 0)      { gb = AH + (size_t)r0 * lda; ld_ = lda; lb = AsH; }
    else if (w == 1) { gb = AL + (size_t)r0 * lda; ld_ = lda; lb = AsL; }
    else if (w == 2) { gb = BH + (size_t)c0 * ldb; ld_ = ldb; lb = BsH; }
    else             { gb = BL + (size_t)c0 * ldb; ld_ = ldb; lb = BsL; }
    const ushort* gl = gb + (size_t)(lane >> 2) * ld_ + (lane & 3) * 8;

    f32x4 acc[4][4];
#pragma unroll
    for (int m = 0; m < 4; ++m)
#pragma unroll
        for (int n = 0; n < 4; ++n) acc[m][n] = (f32x4)0.0f;

    int nk = K >> 5;
    for (int kt = 0; kt < nk; ++kt) {
        const ushort* gk = gl + (kt << 5);
        __syncthreads();
#pragma unroll
        for (int i = 0; i < 8; ++i)
            async_cp16(gk + (size_t)(i * 16) * ld_, lb + i * 512);
        __syncthreads();   // compiler drains vmcnt before barrier (m97 semantics)

        short8 ah[4], al[4];
#pragma unroll
        for (int m = 0; m < 4; ++m) {
            int row = wr * 64 + m * 16 + fr;
            ah[m] = *(const short8*)(AsH + row * 32 + g * 8);
            al[m] = *(const short8*)(AsL + row * 32 + g * 8);
        }
#pragma unroll
        for (int n = 0; n < 4; ++n) {
            int row = wc * 64 + n * 16 + fr;
            short8 bh = *(const short8*)(BsH + row * 32 + g * 8);
            short8 bl = *(const short8*)(BsL + row * 32 + g * 8);
#pragma unroll
            for (int m = 0; m < 4; ++m) {
                acc[m][n] = __builtin_amdgcn_mfma_f32_16x16x32_bf16(ah[m], bh, acc[m][n], 0, 0, 0);
                acc[m][n] = __builtin_amdgcn_mfma_f32_16x16x32_bf16(al[m], bh, acc[m][n], 0, 0, 0);
                acc[m][n] = __builtin_amdgcn_mfma_f32_16x16x32_bf16(ah[m], bl, acc[m][n], 0, 0, 0);
            }
        }
    }

    // epilogue: C/D layout col=lane&15, row=(lane>>4)*4+reg (m89-verified)
    float* oF = outF ? outF + (size_t)sO * z : nullptr;
    ushort* oH = outH ? outH + (size_t)sO * z : nullptr;
    ushort* oL = outL ? outL + (size_t)sO * z : nullptr;
#pragma unroll
    for (int n = 0; n < 4; ++n) {
        int gc = c0 + wc * 64 + n * 16 + fr;
        if (gc >= N) continue;
        float bv = bias ? bias[gc] : 0.0f;
#pragma unroll
        for (int m = 0; m < 4; ++m) {
#pragma unroll
            for (int e = 0; e < 4; ++e) {
                int gr = r0 + wr * 64 + m * 16 + g * 4 + e;
                if (gr >= M) continue;
                float v = acc[m][n][e] * scale + bv;
                if (GELU) v = gelu_tanh(v);
                ll off = (ll)gr * ldo + gc;
                if (SPLIT) {
                    ushort hh, lo;
                    split2(v, hh, lo);
                    oH[off] = hh; oL[off] = lo;
                } else {
                    if (res) v += res[off];
                    oF[off] = v;
                }
            }
        }
    }
}

// ---------------------------------------------------------------------------
// LayerNorm -> split-bf16 planes. One block per row of 1024.
// ---------------------------------------------------------------------------
__global__ __launch_bounds__(256) void ln_split(
    const float* __restrict__ x, const float* __restrict__ gg,
    const float* __restrict__ bt, ushort* __restrict__ oH, ushort* __restrict__ oL)
{
    int row = blockIdx.x;
    int tid = threadIdx.x;
    const float4 v = *(const float4*)(x + (size_t)row * CC + tid * 4);
    float s  = v.x + v.y + v.z + v.w;
    float ss = v.x * v.x + v.y * v.y + v.z * v.z + v.w * v.w;
#pragma unroll
    for (int off = 32; off >= 1; off >>= 1) {
        s  += __shfl_xor(s, off);
        ss += __shfl_xor(ss, off);
    }
    __shared__ float rs[4], rss[4];
    int wave = tid >> 6;
    if ((tid & 63) == 0) { rs[wave] = s; rss[wave] = ss; }
    __syncthreads();
    float S  = rs[0] + rs[1] + rs[2] + rs[3];
    float SS = rss[0] + rss[1] + rss[2] + rss[3];
    float mu   = S * (1.0f / CC);
    float var  = SS * (1.0f / CC) - mu * mu;
    float rstd = rsqrtf(var + 1e-5f);
    int c = tid * 4;
    float4 g4 = *(const float4*)(gg + c);
    float4 b4 = *(const float4*)(bt + c);
    float r0 = (v.x - mu) * rstd * g4.x + b4.x;
    float r1 = (v.y - mu) * rstd * g4.y + b4.y;
    float r2 = (v.z - mu) * rstd * g4.z + b4.z;
    float r3 = (v.w - mu) * rstd * g4.w + b4.w;
    ushort4 h, l;
    split2(r0, h.x, l.x); split2(r1, h.y, l.y);
    split2(r2, h.z, l.z); split2(r3, h.w, l.w);
    *(ushort4*)(oH + (size_t)row * CC + c) = h;
    *(ushort4*)(oL + (size_t)row * CC + c) = l;
}

// ---------------------------------------------------------------------------
// Weight transpose + split: W [Kd][Nd] fp32 -> WH/WL [Nd][Kd] bf16
// ---------------------------------------------------------------------------
__global__ __launch_bounds__(256) void wsplit_T(
    const float* __restrict__ W, ushort* __restrict__ oH, ushort* __restrict__ oL,
    int Kd, int Nd)
{
    __shared__ float t[64][65];
    int n0 = blockIdx.x * 64, k0 = blockIdx.y * 64;
    int tid = threadIdx.x;
#pragma unroll
    for (int j = 0; j < 16; ++j) {
        int i = j * 256 + tid;
        int r = i >> 6, c = i & 63;
        t[r][c] = W[(size_t)(k0 + r) * Nd + n0 + c];
    }
    __syncthreads();
#pragma unroll
    for (int j = 0; j < 16; ++j) {
        int i = j * 256 + tid;
        int rn = i >> 6, ck = i & 63;
        float v = t[ck][rn];
        ushort h, l; split2(v, h, l);
        size_t off = (size_t)(n0 + rn) * Kd + k0 + ck;
        oH[off] = h; oL[off] = l;
    }
}

// elementwise fp32 -> split planes (img_emb)
__global__ __launch_bounds__(256) void split_rows(
    const float* __restrict__ x, ushort* __restrict__ oH, ushort* __restrict__ oL, int n4)
{
    int i = blockIdx.x * 256 + threadIdx.x;
    if (i >= n4) return;
    float4 v = ((const float4*)x)[i];
    ushort4 h, l;
    split2(v.x, h.x, l.x); split2(v.y, h.y, l.y);
    split2(v.z, h.z, l.z); split2(v.w, h.w, l.w);
    ((ushort4*)oH)[i] = h; ((ushort4*)oL)[i] = l;
}

// ---------------------------------------------------------------------------
// v^T: kv split planes [1028][2048] cols 1024.. -> vT [4][1024][288] (pad 0)
// ---------------------------------------------------------------------------
__global__ __launch_bounds__(256) void vtrans(
    const ushort* __restrict__ kvH, const ushort* __restrict__ kvL,
    ushort* __restrict__ vTH, ushort* __restrict__ vTL)
{
    __shared__ ushort tH[32][34], tL[32][34];
    int z = blockIdx.z;
    int kk0 = blockIdx.x * 32, c0 = blockIdx.y * 32;
    int tid = threadIdx.x;
    int r = tid >> 5, c = tid & 31;
#pragma unroll
    for (int p = 0; p < 4; ++p) {
        int kk = kk0 + r + 8 * p;
        bool ok = kk < TT2;
        size_t src = (size_t)(z * TT2 + (ok ? kk : 0)) * 2048 + CC + c0 + c;
        tH[r + 8 * p][c] = ok ? kvH[src] : (ushort)0;
        tL[r + 8 * p][c] = ok ? kvL[src] : (ushort)0;
    }
    __syncthreads();
#pragma unroll
    for (int p = 0; p < 4; ++p) {
        int cc = c0 + r + 8 * p;
        size_t dst = ((size_t)z * CC + cc) * 288 + kk0 + c;
        vTH[dst] = tH[c][r + 8 * p];
        vTL[dst] = tL[c][r + 8 * p];
    }
}

// ---------------------------------------------------------------------------
// Flash-style causal self-attention over qkv fp32 [B*T, 3C] -> split planes
// ---------------------------------------------------------------------------
__global__ __launch_bounds__(256) void flash_attn_kernel(
    const float* __restrict__ qkv, ushort* __restrict__ oH, ushort* __restrict__ oL)
{
    __shared__ float Qs[64][65];
    __shared__ float Ks[64][65];
    __shared__ float Vs[64][65];
    __shared__ float Ps[64][65];

    int b  = blockIdx.y >> 4;
    int h  = blockIdx.y & 15;
    int qt = blockIdx.x;
    int qi0 = qt * 64;
    int tid = threadIdx.x;
    int i    = tid >> 2;
    int quad = tid & 3;
    int d0   = quad * 16;

    const size_t rowBase = (size_t)(b * TT) * (3 * CC);

    {
        const float* src = qkv + rowBase + (size_t)(qi0 + i) * (3 * CC) + h * HD + d0;
#pragma unroll
        for (int j = 0; j < 4; ++j)
            *(float4*)&Qs[i][d0 + 4 * j] = *(const float4*)&src[4 * j];
    }

    float m = -INFINITY, l = 0.0f;
    float o[16];
#pragma unroll
    for (int d = 0; d < 16; ++d) o[d] = 0.0f;

    for (int kt = 0; kt <= qt; ++kt) {
        {
            const float* kp = qkv + rowBase + (size_t)(kt * 64 + i) * (3 * CC) + CC + h * HD + d0;
            const float* vp = kp + CC;
#pragma unroll
            for (int j = 0; j < 4; ++j) {
                *(float4*)&Ks[i][d0 + 4 * j] = *(const float4*)&kp[4 * j];
                *(float4*)&Vs[i][d0 + 4 * j] = *(const float4*)&vp[4 * j];
            }
        }
        __syncthreads();

        float s[16];
#pragma unroll
        for (int jj = 0; jj < 16; ++jj) s[jj] = 0.0f;
#pragma unroll
        for (int d4 = 0; d4 < 16; ++d4) {
            float4 qv = *(const float4*)&Qs[i][d4 * 4];
#pragma unroll
            for (int jj = 0; jj < 16; ++jj) {
                float4 kv = *(const float4*)&Ks[d0 + jj][d4 * 4];
                s[jj] += qv.x * kv.x + qv.y * kv.y + qv.z * kv.z + qv.w * kv.w;
            }
        }
        int qglob = qi0 + i;
        float tmax = -INFINITY;
#pragma unroll
        for (int jj = 0; jj < 16; ++jj) {
            int kglob = kt * 64 + d0 + jj;
            s[jj] = (kglob <= qglob) ? s[jj] * 0.125f : -INFINITY;
            tmax = fmaxf(tmax, s[jj]);
        }
        tmax = fmaxf(tmax, __shfl_xor(tmax, 1));
        tmax = fmaxf(tmax, __shfl_xor(tmax, 2));
        float mnew = fmaxf(m, tmax);
        float tl = 0.0f;
#pragma unroll
        for (int jj = 0; jj < 16; ++jj) {
            float p = expf(s[jj] - mnew);
            Ps[i][d0 + jj] = p;
            tl += p;
        }
        tl += __shfl_xor(tl, 1);
        tl += __shfl_xor(tl, 2);
        float alpha = expf(m - mnew);
        l = l * alpha + tl;
        m = mnew;
        __syncthreads();

#pragma unroll
        for (int d = 0; d < 16; ++d) o[d] *= alpha;
        for (int j = 0; j < 64; ++j) {
            float p = Ps[i][j];
            float4 v0 = *(const float4*)&Vs[j][d0];
            float4 v1 = *(const float4*)&Vs[j][d0 + 4];
            float4 v2 = *(const float4*)&Vs[j][d0 + 8];
            float4 v3 = *(const float4*)&Vs[j][d0 + 12];
            o[0]  += p * v0.x; o[1]  += p * v0.y; o[2]  += p * v0.z; o[3]  += p * v0.w;
            o[4]  += p * v1.x; o[5]  += p * v1.y; o[6]  += p * v1.z; o[7]  += p * v1.w;
            o[8]  += p * v2.x; o[9]  += p * v2.y; o[10] += p * v2.z; o[11] += p * v2.w;
            o[12] += p * v3.x; o[13] += p * v3.y; o[14] += p * v3.z; o[15] += p * v3.w;
        }
        __syncthreads();
    }

    float inv = 1.0f / l;
    size_t base = (size_t)(b * TT + qi0 + i) * CC + h * HD + d0;
#pragma unroll
    for (int g4 = 0; g4 < 4; ++g4) {
        ushort4 hh, lll;
        float v0 = o[g4 * 4 + 0] * inv, v1 = o[g4 * 4 + 1] * inv;
        float v2 = o[g4 * 4 + 2] * inv, v3 = o[g4 * 4 + 3] * inv;
        split2(v0, hh.x, lll.x); split2(v1, hh.y, lll.y);
        split2(v2, hh.z, lll.z); split2(v3, hh.w, lll.w);
        *(ushort4*)(oH + base + g4 * 4) = hh;
        *(ushort4*)(oL + base + g4 * 4) = lll;
    }
}

// ---------------------------------------------------------------------------
// Row softmax over length-257 fp32 rows -> split planes ld 288 (pads zeroed)
// ---------------------------------------------------------------------------
__global__ __launch_bounds__(256) void softmax_split(
    const float* __restrict__ att, ushort* __restrict__ oH, ushort* __restrict__ oL)
{
    int row = blockIdx.x;
    const float* p = att + (size_t)row * TT2;
    int tid = threadIdx.x;
    float v0 = p[tid];
    float v1 = (tid == 0) ? p[256] : -INFINITY;
    float m = fmaxf(v0, v1);
#pragma unroll
    for (int off = 32; off >= 1; off >>= 1) m = fmaxf(m, __shfl_xor(m, off));
    __shared__ float red[8];
    int wave = tid >> 6;
    if ((tid & 63) == 0) red[wave] = m;
    __syncthreads();
    m = fmaxf(fmaxf(red[0], red[1]), fmaxf(red[2], red[3]));
    float e0 = expf(v0 - m);
    float e1 = (tid == 0) ? expf(v1 - m) : 0.0f;
    float s = e0 + e1;
#pragma unroll
    for (int off = 32; off >= 1; off >>= 1) s += __shfl_xor(s, off);
    if ((tid & 63) == 0) red[4 + wave] = s;
    __syncthreads();
    s = red[4] + red[5] + red[6] + red[7];
    float inv = 1.0f / s;
    size_t base = (size_t)row * 288;
    ushort h, l;
    split2(e0 * inv, h, l);
    oH[base + tid] = h; oL[base + tid] = l;
    if (tid < 32) {
        float v = (tid == 0) ? e1 * inv : 0.0f;
        split2(v, h, l);
        oH[base + 256 + tid] = h; oL[base + 256 + tid] = l;
    }
}

__global__ __launch_bounds__(256) void copy4_kernel(
    const float4* __restrict__ src, float4* __restrict__ dst, int n4)
{
    int i = blockIdx.x * blockDim.x + threadIdx.x;
    if (i < n4) dst[i] = src[i];
}

// ---------------------------------------------------------------------------
static inline void gemm(bool gelu, bool split,
    const ushort* AH, const ushort* AL, int lda,
    const ushort* BH, const ushort* BL, int ldb,
    const float* bias, const float* res,
    float* outF, ushort* outH, ushort* outL,
    int M, int N, int K, int ldo, float scale,
    ll sA, ll sB, ll sO, int batch, hipStream_t st)
{
    dim3 gr((N + 127) / 128, (M + 127) / 128, batch);
    if (split) {
        if (gelu)
            gemm_sp<true, true><<<gr, 256, 0, st>>>(AH, AL, lda, BH, BL, ldb, bias, res,
                outF, outH, outL, M, N, K, ldo, scale, sA, sB, sO);
        else
            gemm_sp<false, true><<<gr, 256, 0, st>>>(AH, AL, lda, BH, BL, ldb, bias, res,
                outF, outH, outL, M, N, K, ldo, scale, sA, sB, sO);
    } else {
        gemm_sp<false, false><<<gr, 256, 0, st>>>(AH, AL, lda, BH, BL, ldb, bias, res,
            outF, outH, outL, M, N, K, ldo, scale, sA, sB, sO);
    }
}

extern "C" void kernel_launch(void* const* d_in, const int* in_sizes, int n_in,
                              void* d_out, int out_size, void* d_ws, size_t ws_size,
                              hipStream_t stream)
{
    const float* text_emb    = (const float*)d_in[0];
    const float* img_emb     = (const float*)d_in[1];
    const float* ln1_g       = (const float*)d_in[2];
    const float* ln1_b       = (const float*)d_in[3];
    const float* ln2_g       = (const float*)d_in[4];
    const float* ln2_b       = (const float*)d_in[5];
    const float* ln3_g       = (const float*)d_in[6];
    const float* ln3_b       = (const float*)d_in[7];
    const float* qkv_w       = (const float*)d_in[8];
    const float* qkv_b       = (const float*)d_in[9];
    const float* attn_proj_w = (const float*)d_in[10];
    const float* attn_proj_b = (const float*)d_in[11];
    const float* ca_q_w      = (const float*)d_in[12];
    const float* ca_q_b      = (const float*)d_in[13];
    const float* ca_kv_w     = (const float*)d_in[14];
    const float* ca_kv_b     = (const float*)d_in[15];
    const float* ca_proj_w   = (const float*)d_in[16];
    const float* ca_proj_b   = (const float*)d_in[17];
    const float* mlp_fc_w    = (const float*)d_in[18];
    const float* mlp_fc_b    = (const float*)d_in[19];
    const float* mlp_proj_w  = (const float*)d_in[20];
    const float* mlp_proj_b  = (const float*)d_in[21];

    const int M1 = BB * TT;   // 4096
    const int Mkv = BB * TT2; // 1028

    // ---- workspace arena (96 MB total) ----
    char* base = (char*)d_ws;
    ushort* wH   = (ushort*)base;                        // 8 MB (<=4M elems, shared, converted before each GEMM)
    ushort* wL   = (ushort*)(base + (8u << 20));         // 8 MB
    char* big    = base + (16u << 20);                   // 64 MB multi-use region
    float*  qkvF = (float*)big;                          // steps 2-3: 48 MB
    ushort* hH   = (ushort*)big;                         // steps 14-15: 32 MB
    ushort* hL   = (ushort*)(big + (32u << 20));         // 32 MB
    ushort* qH   = (ushort*)big;                         // steps 6-9: 8 MB
    ushort* qL   = (ushort*)(big + (8u  << 20));
    ushort* kvH  = (ushort*)(big + (16u << 20));         // 1188x2048 (padded rows)
    ushort* kvL  = (ushort*)(big + (21u << 20));
    ushort* vTH  = (ushort*)(big + (26u << 20));         // 4x1024x288
    ushort* vTL  = (ushort*)(big + (29u << 20));
    float*  attF = (float*) (big + (32u << 20));         // 4x1024x257 fp32
    ushort* attH = (ushort*)(big + (37u << 20));         // 4x1024x288
    ushort* attL = (ushort*)(big + (40u << 20));
    ushort* imgH = (ushort*)(big + (43u << 20));         // 1152x1024 (padded rows)
    ushort* imgL = (ushort*)(big + (46u << 20));
    char* actA   = base + (80u << 20);
    ushort* aH   = (ushort*)actA;                        // 8 MB activation split (serial reuse)
    ushort* aL   = (ushort*)(actA + (8u << 20));

    float* out_x   = (float*)d_out;
    float* out_img = out_x + (size_t)M1 * CC;

    // 1. ln1(text) -> aH/aL
    ln_split<<<dim3(M1), dim3(256), 0, stream>>>(text_emb, ln1_g, ln1_b, aH, aL);

    // 2. qkv = ln1 @ qkv_w + b  (fp32 out for flash)
    wsplit_T<<<dim3(3 * CC / 64, CC / 64), 256, 0, stream>>>(qkv_w, wH, wL, CC, 3 * CC);
    gemm(false, false, aH, aL, CC, wH, wL, CC, qkv_b, nullptr, qkvF, nullptr, nullptr,
         M1, 3 * CC, CC, 3 * CC, 1.0f, 0, 0, 0, 1, stream);

    // 3. flash attention -> aH/aL (split)
    flash_attn_kernel<<<dim3(TT / 64, BB * NH), 256, 0, stream>>>(qkvF, aH, aL);

    // 4. x = text + attn @ proj_w + b
    wsplit_T<<<dim3(CC / 64, CC / 64), 256, 0, stream>>>(attn_proj_w, wH, wL, CC, CC);
    gemm(false, false, aH, aL, CC, wH, wL, CC, attn_proj_b, text_emb, out_x, nullptr, nullptr,
         M1, CC, CC, CC, 1.0f, 0, 0, 0, 1, stream);

    // 5. ln3(x) -> aH/aL
    ln_split<<<dim3(M1), dim3(256), 0, stream>>>(out_x, ln3_g, ln3_b, aH, aL);

    // 6. q = ln3 @ ca_q_w + b -> split qH/qL
    wsplit_T<<<dim3(CC / 64, CC / 64), 256, 0, stream>>>(ca_q_w, wH, wL, CC, CC);
    gemm(false, true, aH, aL, CC, wH, wL, CC, ca_q_b, nullptr, nullptr, qH, qL,
         M1, CC, CC, CC, 1.0f, 0, 0, 0, 1, stream);

    // 7. kv = img @ ca_kv_w + b -> split kvH/kvL [1028][2048]
    split_rows<<<dim3(Mkv), 256, 0, stream>>>(img_emb, imgH, imgL, Mkv * CC / 4);
    wsplit_T<<<dim3(2 * CC / 64, CC / 64), 256, 0, stream>>>(ca_kv_w, wH, wL, CC, 2 * CC);
    gemm(false, true, imgH, imgL, CC, wH, wL, CC, ca_kv_b, nullptr, nullptr, kvH, kvL,
         Mkv, 2 * CC, CC, 2 * CC, 1.0f, 0, 0, 0, 1, stream);

    // 8. v^T -> vTH/vTL [4][1024][288] (pads zeroed)
    vtrans<<<dim3(9, 32, BB), 256, 0, stream>>>(kvH, kvL, vTH, vTL);

    // 9. att = (q @ k^T)/32  (batched; k rows are B^T layout already)
    gemm(false, false, qH, qL, CC, kvH, kvL, 2 * CC, nullptr, nullptr, attF, nullptr, nullptr,
         TT, TT2, CC, TT2, 0.03125f,
         (ll)TT * CC, (ll)TT2 * 2 * CC, (ll)TT * TT2, BB, stream);

    // 10. softmax -> split attH/attL ld 288
    softmax_split<<<dim3(BB * TT), 256, 0, stream>>>(attF, attH, attL);

    // 11. caout = att @ v (batched, K=288 padded) -> split aH/aL
    gemm(false, true, attH, attL, 288, vTH, vTL, 288, nullptr, nullptr,
         nullptr, aH, aL, TT, CC, 288, CC, 1.0f,
         (ll)TT * 288, (ll)CC * 288, (ll)TT * CC, BB, stream);

    // 12. x += caout @ ca_proj_w + b
    wsplit_T<<<dim3(CC / 64, CC / 64), 256, 0, stream>>>(ca_proj_w, wH, wL, CC, CC);
    gemm(false, false, aH, aL, CC, wH, wL, CC, ca_proj_b, out_x, out_x, nullptr, nullptr,
         M1, CC, CC, CC, 1.0f, 0, 0, 0, 1, stream);

    // 13. ln2(x) -> aH/aL
    ln_split<<<dim3(M1), dim3(256), 0, stream>>>(out_x, ln2_g, ln2_b, aH, aL);

    // 14. h = gelu(ln2 @ fc_w + b) -> split hH/hL [4096][4096]
    wsplit_T<<<dim3(4 * CC / 64, CC / 64), 256, 0, stream>>>(mlp_fc_w, wH, wL, CC, 4 * CC);
    gemm(true, true, aH, aL, CC, wH, wL, CC, mlp_fc_b, nullptr, nullptr, hH, hL,
         M1, 4 * CC, CC, 4 * CC, 1.0f, 0, 0, 0, 1, stream);

    // 15. x += h @ mlp_proj_w + b
    wsplit_T<<<dim3(CC / 64, 4 * CC / 64), 256, 0, stream>>>(mlp_proj_w, wH, wL, 4 * CC, CC);
    gemm(false, false, hH, hL, 4 * CC, wH, wL, 4 * CC, mlp_proj_b, out_x, out_x, nullptr, nullptr,
         M1, CC, 4 * CC, CC, 1.0f, 0, 0, 0, 1, stream);

    // 16. out_img = img_emb
    {
        int n4 = (BB * TT2 * CC) / 4;
        copy4_kernel<<<dim3((n4 + 255) / 256), dim3(256), 0, stream>>>(
            (const float4*)img_emb, (float4*)out_img, n4);
    }
}

// Round 3
// 1004.342 us; speedup vs baseline: 5.9887x; 1.7954x over previous
//
#include <hip/hip_runtime.h>
#include <math.h>

// Problem constants (B=4, T=1024, C=1024, T2=257, H=16, hd=64)
#define BB   4
#define TT   1024
#define CC   1024
#define TT2  257
#define NH   16
#define HD   64
typedef long long ll;

typedef __attribute__((ext_vector_type(8))) short short8;   // 8 bf16 (4 VGPR)
typedef __attribute__((ext_vector_type(4))) float f32x4;    // MFMA acc

// ---------------------------------------------------------------------------
// bf16 helpers: round-to-nearest-even convert + hi/lo split (fp32 ~= hi+lo)
// ---------------------------------------------------------------------------
__device__ __forceinline__ ushort f2bf(float f) {
    unsigned u = __float_as_uint(f);
    u += 0x7fffu + ((u >> 16) & 1u);
    return (ushort)(u >> 16);
}
__device__ __forceinline__ float bf2f(ushort h) {
    return __uint_as_float(((unsigned)h) << 16);
}
__device__ __forceinline__ void split2(float v, ushort& h, ushort& l) {
    h = f2bf(v);
    l = f2bf(v - bf2f(h));
}

__device__ __forceinline__ void async_cp16(const ushort* g, ushort* l) {
    __builtin_amdgcn_global_load_lds(
        (__attribute__((address_space(1))) void*)g,
        (__attribute__((address_space(3))) void*)l, 16, 0, 0);
}

__device__ __forceinline__ float gelu_tanh(float x) {
    float x3 = x * x * x;
    return 0.5f * x * (1.0f + tanhf(0.7978845608028654f * (x + 0.044715f * x3)));
}

// ---------------------------------------------------------------------------
// Split-bf16 MFMA GEMM.  out = act((A@B^T)*scale + bias) [+ res]
// (unchanged from round 2 — see comments there)
// ---------------------------------------------------------------------------
template<bool GELU, bool SPLIT>
__global__ __launch_bounds__(256, 2) void gemm_sp(
    const ushort* __restrict__ AH, const ushort* __restrict__ AL, int lda,
    const ushort* __restrict__ BH, const ushort* __restrict__ BL, int ldb,
    const float* __restrict__ bias, const float* __restrict__ res,
    float* __restrict__ outF, ushort* __restrict__ outH, ushort* __restrict__ outL,
    int M, int N, int K, int ldo, float scale,
    ll sA, ll sB, ll sO)
{
    __shared__ __align__(16) ushort AsH[128 * 32];
    __shared__ __align__(16) ushort AsL[128 * 32];
    __shared__ __align__(16) ushort BsH[128 * 32];
    __shared__ __align__(16) ushort BsL[128 * 32];

    int z = blockIdx.z;
    AH += (size_t)sA * z; AL += (size_t)sA * z;
    BH += (size_t)sB * z; BL += (size_t)sB * z;

    int tid = threadIdx.x;
    int w = tid >> 6, lane = tid & 63;
    int g = lane >> 4, fr = lane & 15;
    int wr = w >> 1, wc = w & 1;
    int r0 = blockIdx.y * 128, c0 = blockIdx.x * 128;

    const ushort* gb;
    int ld_;
    ushort* lb;
    if (w == 0)      { gb = AH + (size_t)r0 * lda; ld_ = lda; lb = AsH; }
    else if (w == 1) { gb = AL + (size_t)r0 * lda; ld_ = lda; lb = AsL; }
    else if (w == 2) { gb = BH + (size_t)c0 * ldb; ld_ = ldb; lb = BsH; }
    else             { gb = BL + (size_t)c0 * ldb; ld_ = ldb; lb = BsL; }
    const ushort* gl = gb + (size_t)(lane >> 2) * ld_ + (lane & 3) * 8;

    f32x4 acc[4][4];
#pragma unroll
    for (int m = 0; m < 4; ++m)
#pragma unroll
        for (int n = 0; n < 4; ++n) acc[m][n] = (f32x4)0.0f;

    int nk = K >> 5;
    for (int kt = 0; kt < nk; ++kt) {
        const ushort* gk = gl + (kt << 5);
        __syncthreads();
#pragma unroll
        for (int i = 0; i < 8; ++i)
            async_cp16(gk + (size_t)(i * 16) * ld_, lb + i * 512);
        __syncthreads();

        short8 ah[4], al[4];
#pragma unroll
        for (int m = 0; m < 4; ++m) {
            int row = wr * 64 + m * 16 + fr;
            ah[m] = *(const short8*)(AsH + row * 32 + g * 8);
            al[m] = *(const short8*)(AsL + row * 32 + g * 8);
        }
#pragma unroll
        for (int n = 0; n < 4; ++n) {
            int row = wc * 64 + n * 16 + fr;
            short8 bh = *(const short8*)(BsH + row * 32 + g * 8);
            short8 bl = *(const short8*)(BsL + row * 32 + g * 8);
#pragma unroll
            for (int m = 0; m < 4; ++m) {
                acc[m][n] = __builtin_amdgcn_mfma_f32_16x16x32_bf16(ah[m], bh, acc[m][n], 0, 0, 0);
                acc[m][n] = __builtin_amdgcn_mfma_f32_16x16x32_bf16(al[m], bh, acc[m][n], 0, 0, 0);
                acc[m][n] = __builtin_amdgcn_mfma_f32_16x16x32_bf16(ah[m], bl, acc[m][n], 0, 0, 0);
            }
        }
    }

    float* oF = outF ? outF + (size_t)sO * z : nullptr;
    ushort* oH = outH ? outH + (size_t)sO * z : nullptr;
    ushort* oL = outL ? outL + (size_t)sO * z : nullptr;
#pragma unroll
    for (int n = 0; n < 4; ++n) {
        int gc = c0 + wc * 64 + n * 16 + fr;
        if (gc >= N) continue;
        float bv = bias ? bias[gc] : 0.0f;
#pragma unroll
        for (int m = 0; m < 4; ++m) {
#pragma unroll
            for (int e = 0; e < 4; ++e) {
                int gr = r0 + wr * 64 + m * 16 + g * 4 + e;
                if (gr >= M) continue;
                float v = acc[m][n][e] * scale + bv;
                if (GELU) v = gelu_tanh(v);
                ll off = (ll)gr * ldo + gc;
                if (SPLIT) {
                    ushort hh, lo;
                    split2(v, hh, lo);
                    oH[off] = hh; oL[off] = lo;
                } else {
                    if (res) v += res[off];
                    oF[off] = v;
                }
            }
        }
    }
}

// ---------------------------------------------------------------------------
// LayerNorm -> split-bf16 planes. One block per row of 1024.
// ---------------------------------------------------------------------------
__global__ __launch_bounds__(256) void ln_split(
    const float* __restrict__ x, const float* __restrict__ gg,
    const float* __restrict__ bt, ushort* __restrict__ oH, ushort* __restrict__ oL)
{
    int row = blockIdx.x;
    int tid = threadIdx.x;
    const float4 v = *(const float4*)(x + (size_t)row * CC + tid * 4);
    float s  = v.x + v.y + v.z + v.w;
    float ss = v.x * v.x + v.y * v.y + v.z * v.z + v.w * v.w;
#pragma unroll
    for (int off = 32; off >= 1; off >>= 1) {
        s  += __shfl_xor(s, off);
        ss += __shfl_xor(ss, off);
    }
    __shared__ float rs[4], rss[4];
    int wave = tid >> 6;
    if ((tid & 63) == 0) { rs[wave] = s; rss[wave] = ss; }
    __syncthreads();
    float S  = rs[0] + rs[1] + rs[2] + rs[3];
    float SS = rss[0] + rss[1] + rss[2] + rss[3];
    float mu   = S * (1.0f / CC);
    float var  = SS * (1.0f / CC) - mu * mu;
    float rstd = rsqrtf(var + 1e-5f);
    int c = tid * 4;
    float4 g4 = *(const float4*)(gg + c);
    float4 b4 = *(const float4*)(bt + c);
    float r0 = (v.x - mu) * rstd * g4.x + b4.x;
    float r1 = (v.y - mu) * rstd * g4.y + b4.y;
    float r2 = (v.z - mu) * rstd * g4.z + b4.z;
    float r3 = (v.w - mu) * rstd * g4.w + b4.w;
    ushort4 h, l;
    split2(r0, h.x, l.x); split2(r1, h.y, l.y);
    split2(r2, h.z, l.z); split2(r3, h.w, l.w);
    *(ushort4*)(oH + (size_t)row * CC + c) = h;
    *(ushort4*)(oL + (size_t)row * CC + c) = l;
}

// ---------------------------------------------------------------------------
// Weight transpose + split: W [Kd][Nd] fp32 -> WH/WL [Nd][Kd] bf16
// ---------------------------------------------------------------------------
__global__ __launch_bounds__(256) void wsplit_T(
    const float* __restrict__ W, ushort* __restrict__ oH, ushort* __restrict__ oL,
    int Kd, int Nd)
{
    __shared__ float t[64][65];
    int n0 = blockIdx.x * 64, k0 = blockIdx.y * 64;
    int tid = threadIdx.x;
#pragma unroll
    for (int j = 0; j < 16; ++j) {
        int i = j * 256 + tid;
        int r = i >> 6, c = i & 63;
        t[r][c] = W[(size_t)(k0 + r) * Nd + n0 + c];
    }
    __syncthreads();
#pragma unroll
    for (int j = 0; j < 16; ++j) {
        int i = j * 256 + tid;
        int rn = i >> 6, ck = i & 63;
        float v = t[ck][rn];
        ushort h, l; split2(v, h, l);
        size_t off = (size_t)(n0 + rn) * Kd + k0 + ck;
        oH[off] = h; oL[off] = l;
    }
}

// elementwise fp32 -> split planes (img_emb)
__global__ __launch_bounds__(256) void split_rows(
    const float* __restrict__ x, ushort* __restrict__ oH, ushort* __restrict__ oL, int n4)
{
    int i = blockIdx.x * 256 + threadIdx.x;
    if (i >= n4) return;
    float4 v = ((const float4*)x)[i];
    ushort4 h, l;
    split2(v.x, h.x, l.x); split2(v.y, h.y, l.y);
    split2(v.z, h.z, l.z); split2(v.w, h.w, l.w);
    ((ushort4*)oH)[i] = h; ((ushort4*)oL)[i] = l;
}

// ---------------------------------------------------------------------------
// Self-attn V^T prep: qkvH [B*T][3072] cols 2048+h*64.. -> vT [(b*16+h)*64+d][T]
// ---------------------------------------------------------------------------
__global__ __launch_bounds__(256) void vt_self(
    const ushort* __restrict__ qkvH, ushort* __restrict__ vT)
{
    __shared__ ushort t[64][72];
    int bh = blockIdx.y, b = bh >> 4, h = bh & 15;
    int t0 = blockIdx.x * 64;
    int tid = threadIdx.x;
    int r = tid >> 2, c0 = (tid & 3) * 16;
    const ushort* src = qkvH + (size_t)(b * TT + t0 + r) * 3072 + 2048 + h * HD + c0;
    *(short8*)&t[r][c0]     = *(const short8*)(src);
    *(short8*)&t[r][c0 + 8] = *(const short8*)(src + 8);
    __syncthreads();
    ushort* dst = vT + ((size_t)bh * HD + r) * TT + t0 + c0;
#pragma unroll
    for (int i = 0; i < 16; ++i) dst[i] = t[c0 + i][r];
}

// ---------------------------------------------------------------------------
// MFMA flash causal self-attention.
//   Inputs: qkvH/qkvL split planes [B*T][3072]; vT hi-plane [(b,h)][64d][1024].
//   Block = 4 waves x 16 q-rows (Q-tile 64). Grid (T/64, B*H).
//   QK^T = qh*kh + ql*kh (3rd term dropped; err ~1e-3 pre-softmax).
//   PV   = ph*vh + pl*vh (P split computed in-kernel).
//   K/V^T tiles in LDS padded to 72 ushorts/row (<=2-way b128 aliasing).
//   Online softmax in base-2 domain (exp2f == v_exp_f32 native).
// ---------------------------------------------------------------------------
__global__ __launch_bounds__(256) void flash_mfma(
    const ushort* __restrict__ qkvH, const ushort* __restrict__ qkvL,
    const ushort* __restrict__ vT,
    ushort* __restrict__ oH, ushort* __restrict__ oL)
{
    __shared__ __align__(16) ushort Ks[64 * 72];
    __shared__ __align__(16) ushort Vs[64 * 72];
    __shared__ __align__(16) ushort PsH[64 * 72];
    __shared__ __align__(16) ushort PsL[64 * 72];

    int bh = blockIdx.y, b = bh >> 4, h = bh & 15;
    int qt = blockIdx.x;
    int tid = threadIdx.x;
    int w = tid >> 6, lane = tid & 63, g = lane >> 4, fr = lane & 15;

    // Q fragments in registers: rows (qt*64 + w*16 + fr), 2 k-chunks, hi+lo
    short8 qh[2], ql[2];
    {
        size_t qoff = (size_t)(b * TT + qt * 64 + w * 16 + fr) * 3072 + h * HD + g * 8;
        qh[0] = *(const short8*)(qkvH + qoff);
        qh[1] = *(const short8*)(qkvH + qoff + 32);
        ql[0] = *(const short8*)(qkvL + qoff);
        ql[1] = *(const short8*)(qkvL + qoff + 32);
    }

    f32x4 o[4];
#pragma unroll
    for (int n = 0; n < 4; ++n) o[n] = (f32x4)0.0f;
    float mrow[4] = {-INFINITY, -INFINITY, -INFINITY, -INFINITY};
    float lrow[4] = {0.0f, 0.0f, 0.0f, 0.0f};

    // staging coords: thread covers (row sr, 16 cols at sc) of a 64x64 tile
    int sr = tid >> 2, sc = (tid & 3) * 16;
    const ushort* kbase = qkvH + (size_t)(b * TT) * 3072 + 1024 + h * HD + sc;
    const ushort* vbase = vT + ((size_t)bh * HD + sr) * TT + sc;

    const float SC = 0.18033688011112042f;   // 0.125 * log2(e)

    for (int kt = 0; kt <= qt; ++kt) {
        __syncthreads();
        {
            const ushort* ksrc = kbase + (size_t)(kt * 64 + sr) * 3072;
            *(short8*)&Ks[sr * 72 + sc]     = *(const short8*)(ksrc);
            *(short8*)&Ks[sr * 72 + sc + 8] = *(const short8*)(ksrc + 8);
            const ushort* vsrc = vbase + kt * 64;
            *(short8*)&Vs[sr * 72 + sc]     = *(const short8*)(vsrc);
            *(short8*)&Vs[sr * 72 + sc + 8] = *(const short8*)(vsrc + 8);
        }
        __syncthreads();

        // S = Q K^T  (per wave: 16q x 64k)
        f32x4 s[4];
#pragma unroll
        for (int n = 0; n < 4; ++n) s[n] = (f32x4)0.0f;
#pragma unroll
        for (int n = 0; n < 4; ++n) {
#pragma unroll
            for (int c = 0; c < 2; ++c) {
                short8 kf = *(const short8*)&Ks[(n * 16 + fr) * 72 + c * 32 + g * 8];
                s[n] = __builtin_amdgcn_mfma_f32_16x16x32_bf16(qh[c], kf, s[n], 0, 0, 0);
                s[n] = __builtin_amdgcn_mfma_f32_16x16x32_bf16(ql[c], kf, s[n], 0, 0, 0);
            }
        }

        // scale + causal mask (diag tile only) + row stats
        float pm[4] = {-INFINITY, -INFINITY, -INFINITY, -INFINITY};
        bool diag = (kt == qt);
#pragma unroll
        for (int n = 0; n < 4; ++n) {
#pragma unroll
            for (int e = 0; e < 4; ++e) {
                float sv = s[n][e] * SC;
                if (diag && (16 * n + fr) > (w * 16 + g * 4 + e)) sv = -INFINITY;
                s[n][e] = sv;
                pm[e] = fmaxf(pm[e], sv);
            }
        }
#pragma unroll
        for (int e = 0; e < 4; ++e) {
            pm[e] = fmaxf(pm[e], __shfl_xor(pm[e], 1));
            pm[e] = fmaxf(pm[e], __shfl_xor(pm[e], 2));
            pm[e] = fmaxf(pm[e], __shfl_xor(pm[e], 4));
            pm[e] = fmaxf(pm[e], __shfl_xor(pm[e], 8));
        }
        float alpha[4];
#pragma unroll
        for (int e = 0; e < 4; ++e) {
            float mn = fmaxf(mrow[e], pm[e]);
            alpha[e] = exp2f(mrow[e] - mn);     // -inf - finite -> 0
            mrow[e] = mn;
        }
        float ls[4] = {0.0f, 0.0f, 0.0f, 0.0f};
#pragma unroll
        for (int n = 0; n < 4; ++n)
#pragma unroll
            for (int e = 0; e < 4; ++e) {
                float p = exp2f(s[n][e] - mrow[e]);
                s[n][e] = p;
                ls[e] += p;
            }
#pragma unroll
        for (int e = 0; e < 4; ++e) {
            ls[e] += __shfl_xor(ls[e], 1);
            ls[e] += __shfl_xor(ls[e], 2);
            ls[e] += __shfl_xor(ls[e], 4);
            ls[e] += __shfl_xor(ls[e], 8);
            lrow[e] = lrow[e] * alpha[e] + ls[e];
        }

        // write split P to wave-private LDS rows
#pragma unroll
        for (int n = 0; n < 4; ++n)
#pragma unroll
            for (int e = 0; e < 4; ++e) {
                ushort ph, pl;
                split2(s[n][e], ph, pl);
                int idx = (w * 16 + g * 4 + e) * 72 + n * 16 + fr;
                PsH[idx] = ph; PsL[idx] = pl;
            }

        // rescale O accumulators
#pragma unroll
        for (int n = 0; n < 4; ++n)
#pragma unroll
            for (int e = 0; e < 4; ++e) o[n][e] *= alpha[e];

        // PV: O += P @ V   (A = P rows, B^T = V^T rows)
        short8 paH[2], paL[2];
#pragma unroll
        for (int c = 0; c < 2; ++c) {
            paH[c] = *(const short8*)&PsH[(w * 16 + fr) * 72 + c * 32 + g * 8];
            paL[c] = *(const short8*)&PsL[(w * 16 + fr) * 72 + c * 32 + g * 8];
        }
#pragma unroll
        for (int n = 0; n < 4; ++n) {
#pragma unroll
            for (int c = 0; c < 2; ++c) {
                short8 vf = *(const short8*)&Vs[(n * 16 + fr) * 72 + c * 32 + g * 8];
                o[n] = __builtin_amdgcn_mfma_f32_16x16x32_bf16(paH[c], vf, o[n], 0, 0, 0);
                o[n] = __builtin_amdgcn_mfma_f32_16x16x32_bf16(paL[c], vf, o[n], 0, 0, 0);
            }
        }
    }

    // epilogue: normalize, split, store
    float inv[4];
#pragma unroll
    for (int e = 0; e < 4; ++e) inv[e] = 1.0f / lrow[e];
#pragma unroll
    for (int n = 0; n < 4; ++n)
#pragma unroll
        for (int e = 0; e < 4; ++e) {
            float v = o[n][e] * inv[e];
            ushort hh, lo;
            split2(v, hh, lo);
            size_t off = (size_t)(b * TT + qt * 64 + w * 16 + g * 4 + e) * CC
                       + h * HD + n * 16 + fr;
            oH[off] = hh; oL[off] = lo;
        }
}

// ---------------------------------------------------------------------------
// Cross-attn v^T: kv split planes [1028][2048] cols 1024.. -> vT [4][1024][288]
// ---------------------------------------------------------------------------
__global__ __launch_bounds__(256) void vtrans(
    const ushort* __restrict__ kvH, const ushort* __restrict__ kvL,
    ushort* __restrict__ vTH, ushort* __restrict__ vTL)
{
    __shared__ ushort tH[32][34], tL[32][34];
    int z = blockIdx.z;
    int kk0 = blockIdx.x * 32, c0 = blockIdx.y * 32;
    int tid = threadIdx.x;
    int r = tid >> 5, c = tid & 31;
#pragma unroll
    for (int p = 0; p < 4; ++p) {
        int kk = kk0 + r + 8 * p;
        bool ok = kk < TT2;
        size_t src = (size_t)(z * TT2 + (ok ? kk : 0)) * 2048 + CC + c0 + c;
        tH[r + 8 * p][c] = ok ? kvH[src] : (ushort)0;
        tL[r + 8 * p][c] = ok ? kvL[src] : (ushort)0;
    }
    __syncthreads();
#pragma unroll
    for (int p = 0; p < 4; ++p) {
        int cc = c0 + r + 8 * p;
        size_t dst = ((size_t)z * CC + cc) * 288 + kk0 + c;
        vTH[dst] = tH[c][r + 8 * p];
        vTL[dst] = tL[c][r + 8 * p];
    }
}

// ---------------------------------------------------------------------------
// Row softmax over length-257 fp32 rows -> split planes ld 288 (pads zeroed)
// ---------------------------------------------------------------------------
__global__ __launch_bounds__(256) void softmax_split(
    const float* __restrict__ att, ushort* __restrict__ oH, ushort* __restrict__ oL)
{
    int row = blockIdx.x;
    const float* p = att + (size_t)row * TT2;
    int tid = threadIdx.x;
    float v0 = p[tid];
    float v1 = (tid == 0) ? p[256] : -INFINITY;
    float m = fmaxf(v0, v1);
#pragma unroll
    for (int off = 32; off >= 1; off >>= 1) m = fmaxf(m, __shfl_xor(m, off));
    __shared__ float red[8];
    int wave = tid >> 6;
    if ((tid & 63) == 0) red[wave] = m;
    __syncthreads();
    m = fmaxf(fmaxf(red[0], red[1]), fmaxf(red[2], red[3]));
    float e0 = expf(v0 - m);
    float e1 = (tid == 0) ? expf(v1 - m) : 0.0f;
    float s = e0 + e1;
#pragma unroll
    for (int off = 32; off >= 1; off >>= 1) s += __shfl_xor(s, off);
    if ((tid & 63) == 0) red[4 + wave] = s;
    __syncthreads();
    s = red[4] + red[5] + red[6] + red[7];
    float inv = 1.0f / s;
    size_t base = (size_t)row * 288;
    ushort h, l;
    split2(e0 * inv, h, l);
    oH[base + tid] = h; oL[base + tid] = l;
    if (tid < 32) {
        float v = (tid == 0) ? e1 * inv : 0.0f;
        split2(v, h, l);
        oH[base + 256 + tid] = h; oL[base + 256 + tid] = l;
    }
}

__global__ __launch_bounds__(256) void copy4_kernel(
    const float4* __restrict__ src, float4* __restrict__ dst, int n4)
{
    int i = blockIdx.x * blockDim.x + threadIdx.x;
    if (i < n4) dst[i] = src[i];
}

// ---------------------------------------------------------------------------
static inline void gemm(bool gelu, bool split,
    const ushort* AH, const ushort* AL, int lda,
    const ushort* BH, const ushort* BL, int ldb,
    const float* bias, const float* res,
    float* outF, ushort* outH, ushort* outL,
    int M, int N, int K, int ldo, float scale,
    ll sA, ll sB, ll sO, int batch, hipStream_t st)
{
    dim3 gr((N + 127) / 128, (M + 127) / 128, batch);
    if (split) {
        if (gelu)
            gemm_sp<true, true><<<gr, 256, 0, st>>>(AH, AL, lda, BH, BL, ldb, bias, res,
                outF, outH, outL, M, N, K, ldo, scale, sA, sB, sO);
        else
            gemm_sp<false, true><<<gr, 256, 0, st>>>(AH, AL, lda, BH, BL, ldb, bias, res,
                outF, outH, outL, M, N, K, ldo, scale, sA, sB, sO);
    } else {
        gemm_sp<false, false><<<gr, 256, 0, st>>>(AH, AL, lda, BH, BL, ldb, bias, res,
            outF, outH, outL, M, N, K, ldo, scale, sA, sB, sO);
    }
}

extern "C" void kernel_launch(void* const* d_in, const int* in_sizes, int n_in,
                              void* d_out, int out_size, void* d_ws, size_t ws_size,
                              hipStream_t stream)
{
    const float* text_emb    = (const float*)d_in[0];
    const float* img_emb     = (const float*)d_in[1];
    const float* ln1_g       = (const float*)d_in[2];
    const float* ln1_b       = (const float*)d_in[3];
    const float* ln2_g       = (const float*)d_in[4];
    const float* ln2_b       = (const float*)d_in[5];
    const float* ln3_g       = (const float*)d_in[6];
    const float* ln3_b       = (const float*)d_in[7];
    const float* qkv_w       = (const float*)d_in[8];
    const float* qkv_b       = (const float*)d_in[9];
    const float* attn_proj_w = (const float*)d_in[10];
    const float* attn_proj_b = (const float*)d_in[11];
    const float* ca_q_w      = (const float*)d_in[12];
    const float* ca_q_b      = (const float*)d_in[13];
    const float* ca_kv_w     = (const float*)d_in[14];
    const float* ca_kv_b     = (const float*)d_in[15];
    const float* ca_proj_w   = (const float*)d_in[16];
    const float* ca_proj_b   = (const float*)d_in[17];
    const float* mlp_fc_w    = (const float*)d_in[18];
    const float* mlp_fc_b    = (const float*)d_in[19];
    const float* mlp_proj_w  = (const float*)d_in[20];
    const float* mlp_proj_b  = (const float*)d_in[21];

    const int M1 = BB * TT;   // 4096
    const int Mkv = BB * TT2; // 1028

    // ---- workspace arena (96 MB) ----
    char* base = (char*)d_ws;
    ushort* wH   = (ushort*)base;                        // 8 MB shared weight planes
    ushort* wL   = (ushort*)(base + (8u << 20));         // 8 MB
    char* big    = base + (16u << 20);                   // 64 MB multi-use
    // steps 2-4:
    ushort* qkvH = (ushort*)big;                         // 24 MB [4096][3072]
    ushort* qkvL = (ushort*)(big + (24u << 20));         // 24 MB
    ushort* vTs  = (ushort*)(big + (48u << 20));         // 8 MB  [(b,h)*64][1024]
    // steps 14-15:
    ushort* hH   = (ushort*)big;                         // 32 MB
    ushort* hL   = (ushort*)(big + (32u << 20));         // 32 MB
    // steps 6-11:
    ushort* qH   = (ushort*)big;
    ushort* qL   = (ushort*)(big + (8u  << 20));
    ushort* kvH  = (ushort*)(big + (16u << 20));
    ushort* kvL  = (ushort*)(big + (21u << 20));
    ushort* vTH  = (ushort*)(big + (26u << 20));
    ushort* vTL  = (ushort*)(big + (29u << 20));
    float*  attF = (float*) (big + (32u << 20));
    ushort* attH = (ushort*)(big + (37u << 20));
    ushort* attL = (ushort*)(big + (40u << 20));
    ushort* imgH = (ushort*)(big + (43u << 20));
    ushort* imgL = (ushort*)(big + (46u << 20));
    char* actA   = base + (80u << 20);
    ushort* aH   = (ushort*)actA;                        // 8 MB activation planes
    ushort* aL   = (ushort*)(actA + (8u << 20));

    float* out_x   = (float*)d_out;
    float* out_img = out_x + (size_t)M1 * CC;

    // 1. ln1(text) -> aH/aL
    ln_split<<<dim3(M1), dim3(256), 0, stream>>>(text_emb, ln1_g, ln1_b, aH, aL);

    // 2. qkv = ln1 @ qkv_w + b -> split planes
    wsplit_T<<<dim3(3 * CC / 64, CC / 64), 256, 0, stream>>>(qkv_w, wH, wL, CC, 3 * CC);
    gemm(false, true, aH, aL, CC, wH, wL, CC, qkv_b, nullptr, nullptr, qkvH, qkvL,
         M1, 3 * CC, CC, 3 * CC, 1.0f, 0, 0, 0, 1, stream);

    // 2b. V^T prep for self-attn
    vt_self<<<dim3(TT / 64, BB * NH), 256, 0, stream>>>(qkvH, vTs);

    // 3. MFMA flash attention -> aH/aL (split)
    flash_mfma<<<dim3(TT / 64, BB * NH), 256, 0, stream>>>(qkvH, qkvL, vTs, aH, aL);

    // 4. x = text + attn @ proj_w + b
    wsplit_T<<<dim3(CC / 64, CC / 64), 256, 0, stream>>>(attn_proj_w, wH, wL, CC, CC);
    gemm(false, false, aH, aL, CC, wH, wL, CC, attn_proj_b, text_emb, out_x, nullptr, nullptr,
         M1, CC, CC, CC, 1.0f, 0, 0, 0, 1, stream);

    // 5. ln3(x) -> aH/aL
    ln_split<<<dim3(M1), dim3(256), 0, stream>>>(out_x, ln3_g, ln3_b, aH, aL);

    // 6. q = ln3 @ ca_q_w + b -> split qH/qL
    wsplit_T<<<dim3(CC / 64, CC / 64), 256, 0, stream>>>(ca_q_w, wH, wL, CC, CC);
    gemm(false, true, aH, aL, CC, wH, wL, CC, ca_q_b, nullptr, nullptr, qH, qL,
         M1, CC, CC, CC, 1.0f, 0, 0, 0, 1, stream);

    // 7. kv = img @ ca_kv_w + b -> split kvH/kvL [1028][2048]
    split_rows<<<dim3(Mkv), 256, 0, stream>>>(img_emb, imgH, imgL, Mkv * CC / 4);
    wsplit_T<<<dim3(2 * CC / 64, CC / 64), 256, 0, stream>>>(ca_kv_w, wH, wL, CC, 2 * CC);
    gemm(false, true, imgH, imgL, CC, wH, wL, CC, ca_kv_b, nullptr, nullptr, kvH, kvL,
         Mkv, 2 * CC, CC, 2 * CC, 1.0f, 0, 0, 0, 1, stream);

    // 8. cross v^T -> vTH/vTL [4][1024][288]
    vtrans<<<dim3(9, 32, BB), 256, 0, stream>>>(kvH, kvL, vTH, vTL);

    // 9. att = (q @ k^T)/32 (batched)
    gemm(false, false, qH, qL, CC, kvH, kvL, 2 * CC, nullptr, nullptr, attF, nullptr, nullptr,
         TT, TT2, CC, TT2, 0.03125f,
         (ll)TT * CC, (ll)TT2 * 2 * CC, (ll)TT * TT2, BB, stream);

    // 10. softmax -> split attH/attL ld 288
    softmax_split<<<dim3(BB * TT), 256, 0, stream>>>(attF, attH, attL);

    // 11. caout = att @ v (batched, K=288 padded) -> split aH/aL
    gemm(false, true, attH, attL, 288, vTH, vTL, 288, nullptr, nullptr,
         nullptr, aH, aL, TT, CC, 288, CC, 1.0f,
         (ll)TT * 288, (ll)CC * 288, (ll)TT * CC, BB, stream);

    // 12. x += caout @ ca_proj_w + b
    wsplit_T<<<dim3(CC / 64, CC / 64), 256, 0, stream>>>(ca_proj_w, wH, wL, CC, CC);
    gemm(false, false, aH, aL, CC, wH, wL, CC, ca_proj_b, out_x, out_x, nullptr, nullptr,
         M1, CC, CC, CC, 1.0f, 0, 0, 0, 1, stream);

    // 13. ln2(x) -> aH/aL
    ln_split<<<dim3(M1), dim3(256), 0, stream>>>(out_x, ln2_g, ln2_b, aH, aL);

    // 14. h = gelu(ln2 @ fc_w + b) -> split hH/hL [4096][4096]
    wsplit_T<<<dim3(4 * CC / 64, CC / 64), 256, 0, stream>>>(mlp_fc_w, wH, wL, CC, 4 * CC);
    gemm(true, true, aH, aL, CC, wH, wL, CC, mlp_fc_b, nullptr, nullptr, hH, hL,
         M1, 4 * CC, CC, 4 * CC, 1.0f, 0, 0, 0, 1, stream);

    // 15. x += h @ mlp_proj_w + b
    wsplit_T<<<dim3(CC / 64, 4 * CC / 64), 256, 0, stream>>>(mlp_proj_w, wH, wL, 4 * CC, CC);
    gemm(false, false, hH, hL, 4 * CC, wH, wL, 4 * CC, mlp_proj_b, out_x, out_x, nullptr, nullptr,
         M1, CC, 4 * CC, CC, 1.0f, 0, 0, 0, 1, stream);

    // 16. out_img = img_emb
    {
        int n4 = (BB * TT2 * CC) / 4;
        copy4_kernel<<<dim3((n4 + 255) / 256), dim3(256), 0, stream>>>(
            (const float4*)img_emb, (float4*)out_img, n4);
    }
}

// Round 4
// 799.669 us; speedup vs baseline: 7.5215x; 1.2559x over previous
//
#include <hip/hip_runtime.h>
#include <math.h>

// Problem constants (B=4, T=1024, C=1024, T2=257, H=16, hd=64)
#define BB   4
#define TT   1024
#define CC   1024
#define TT2  257
#define NH   16
#define HD   64
typedef long long ll;

typedef __attribute__((ext_vector_type(8))) short short8;   // 8 bf16 (4 VGPR)
typedef __attribute__((ext_vector_type(4))) float f32x4;    // MFMA acc

// ---------------------------------------------------------------------------
// bf16 helpers: round-to-nearest-even convert + hi/lo split (fp32 ~= hi+lo)
// ---------------------------------------------------------------------------
__device__ __forceinline__ ushort f2bf(float f) {
    unsigned u = __float_as_uint(f);
    u += 0x7fffu + ((u >> 16) & 1u);
    return (ushort)(u >> 16);
}
__device__ __forceinline__ float bf2f(ushort h) {
    return __uint_as_float(((unsigned)h) << 16);
}
__device__ __forceinline__ void split2(float v, ushort& h, ushort& l) {
    h = f2bf(v);
    l = f2bf(v - bf2f(h));
}

__device__ __forceinline__ void async_cp16(const ushort* g, ushort* l) {
    __builtin_amdgcn_global_load_lds(
        (__attribute__((address_space(1))) void*)g,
        (__attribute__((address_space(3))) void*)l, 16, 0, 0);
}

__device__ __forceinline__ float gelu_tanh(float x) {
    float x3 = x * x * x;
    return 0.5f * x * (1.0f + tanhf(0.7978845608028654f * (x + 0.044715f * x3)));
}

// ---------------------------------------------------------------------------
// Split-bf16 MFMA GEMM.
//   MODE 1: out = (A@B^T)+bias -> split planes oH/oL
//   MODE 2: out = gelu((A@B^T)+bias) -> split planes (oL optional)
//   MODE 3: raw fp32 partial (split-K): grid.z = batch*S, z=(zb*S+s);
//           block computes K-iters [nIter*s/S, nIter*(s+1)/S) and writes
//           acc to outF + z*sO. scale/bias/res applied by reduce_k.
//   APASS 2: A hi+lo planes (3 MFMA/pair); APASS 1: A hi only (2 MFMA/pair).
//   128x128 tile, BK=32, 4 waves, XCD-swizzled block mapping (bijective m204).
// ---------------------------------------------------------------------------
template<int MODE, int APASS>
__global__ __launch_bounds__(256, 2) void gemm_sp(
    const ushort* __restrict__ AH, const ushort* __restrict__ AL, int lda,
    const ushort* __restrict__ BH, const ushort* __restrict__ BL, int ldb,
    const float* __restrict__ bias,
    float* __restrict__ outF, ushort* __restrict__ outH, ushort* __restrict__ outL,
    int M, int N, int K, int ldo,
    ll sA, ll sB, ll sO, int S)
{
    __shared__ __align__(16) ushort AsH[128 * 32];
    __shared__ __align__(16) ushort AsL[128 * 32];
    __shared__ __align__(16) ushort BsH[128 * 32];
    __shared__ __align__(16) ushort BsL[128 * 32];

    // z decomposition (split-K only in MODE 3)
    int zb, sl;
    if (MODE == 3) { zb = blockIdx.z / S; sl = blockIdx.z % S; }
    else           { zb = blockIdx.z;     sl = 0; S = 1; }
    AH += (size_t)sA * zb; if (APASS == 2) AL += (size_t)sA * zb;
    BH += (size_t)sB * zb; BL += (size_t)sB * zb;

    // XCD-aware bijective block swizzle (T1, m204)
    int gx = gridDim.x;
    int nxy = gx * gridDim.y;
    int orig = blockIdx.y * gx + blockIdx.x;
    int qq = nxy >> 3, rr = nxy & 7;
    int xcd = orig & 7, lid = orig >> 3;
    int nid = (xcd < rr ? xcd * (qq + 1) : rr * (qq + 1) + (xcd - rr) * qq) + lid;
    int r0 = (nid / gx) * 128, c0 = (nid % gx) * 128;

    int tid = threadIdx.x;
    int w = tid >> 6, lane = tid & 63;
    int g = lane >> 4, fr = lane & 15;
    int wr = w >> 1, wc = w & 1;

    // staging assignment: one wave per LDS plane
    const ushort* gb = nullptr;
    int ld_ = 0;
    ushort* lb = nullptr;
    bool st = true;
    if (APASS == 2) {
        if (w == 0)      { gb = AH + (size_t)r0 * lda; ld_ = lda; lb = AsH; }
        else if (w == 1) { gb = AL + (size_t)r0 * lda; ld_ = lda; lb = AsL; }
        else if (w == 2) { gb = BH + (size_t)c0 * ldb; ld_ = ldb; lb = BsH; }
        else             { gb = BL + (size_t)c0 * ldb; ld_ = ldb; lb = BsL; }
    } else {
        if (w == 0)      { gb = AH + (size_t)r0 * lda; ld_ = lda; lb = AsH; }
        else if (w == 2) { gb = BH + (size_t)c0 * ldb; ld_ = ldb; lb = BsH; }
        else if (w == 3) { gb = BL + (size_t)c0 * ldb; ld_ = ldb; lb = BsL; }
        else st = false;
    }
    const ushort* gl = st ? gb + (size_t)(lane >> 2) * ld_ + (lane & 3) * 8 : nullptr;

    f32x4 acc[4][4];
#pragma unroll
    for (int m = 0; m < 4; ++m)
#pragma unroll
        for (int n = 0; n < 4; ++n) acc[m][n] = (f32x4)0.0f;

    int nIter = K >> 5;
    int it0 = (nIter * sl) / S, it1 = (nIter * (sl + 1)) / S;
    for (int kt = it0; kt < it1; ++kt) {
        __syncthreads();
        if (st) {
            const ushort* gk = gl + (kt << 5);
#pragma unroll
            for (int i = 0; i < 8; ++i)
                async_cp16(gk + (size_t)(i * 16) * ld_, lb + i * 512);
        }
        __syncthreads();   // drains vmcnt before barrier

        short8 ah[4], al[4];
#pragma unroll
        for (int m = 0; m < 4; ++m) {
            int row = wr * 64 + m * 16 + fr;
            ah[m] = *(const short8*)(AsH + row * 32 + g * 8);
            if (APASS == 2) al[m] = *(const short8*)(AsL + row * 32 + g * 8);
        }
#pragma unroll
        for (int n = 0; n < 4; ++n) {
            int row = wc * 64 + n * 16 + fr;
            short8 bh = *(const short8*)(BsH + row * 32 + g * 8);
            short8 bl = *(const short8*)(BsL + row * 32 + g * 8);
#pragma unroll
            for (int m = 0; m < 4; ++m) {
                acc[m][n] = __builtin_amdgcn_mfma_f32_16x16x32_bf16(ah[m], bh, acc[m][n], 0, 0, 0);
                if (APASS == 2)
                    acc[m][n] = __builtin_amdgcn_mfma_f32_16x16x32_bf16(al[m], bh, acc[m][n], 0, 0, 0);
                acc[m][n] = __builtin_amdgcn_mfma_f32_16x16x32_bf16(ah[m], bl, acc[m][n], 0, 0, 0);
            }
        }
    }

    // epilogue: C/D layout col=lane&15, row=(lane>>4)*4+reg (m89-verified)
    if (MODE == 3) {
        float* po = outF + (ll)blockIdx.z * sO;
#pragma unroll
        for (int n = 0; n < 4; ++n) {
            int gc = c0 + wc * 64 + n * 16 + fr;
            if (gc >= N) continue;
#pragma unroll
            for (int m = 0; m < 4; ++m)
#pragma unroll
                for (int e = 0; e < 4; ++e) {
                    int gr = r0 + wr * 64 + m * 16 + g * 4 + e;
                    if (gr >= M) continue;
                    po[(ll)gr * ldo + gc] = acc[m][n][e];
                }
        }
    } else {
        ushort* oH = outH + (size_t)sO * zb;
        ushort* oL = outL ? outL + (size_t)sO * zb : nullptr;
#pragma unroll
        for (int n = 0; n < 4; ++n) {
            int gc = c0 + wc * 64 + n * 16 + fr;
            if (gc >= N) continue;
            float bv = bias ? bias[gc] : 0.0f;
#pragma unroll
            for (int m = 0; m < 4; ++m)
#pragma unroll
                for (int e = 0; e < 4; ++e) {
                    int gr = r0 + wr * 64 + m * 16 + g * 4 + e;
                    if (gr >= M) continue;
                    float v = acc[m][n][e] + bv;
                    if (MODE == 2) v = gelu_tanh(v);
                    ll off = (ll)gr * ldo + gc;
                    ushort hh, lo;
                    split2(v, hh, lo);
                    oH[off] = hh;
                    if (MODE == 1 || oL) oL[off] = lo;
                }
        }
    }
}

// ---------------------------------------------------------------------------
// Split-K reduce: out = (sum_s partial[s])*scale + bias (+res) -> fp32 or split
// partial layout: [zb][s][rows][ldp]; grid (ceil(cols/1024), rows, batch)
// ---------------------------------------------------------------------------
template<bool SPLIT>
__global__ __launch_bounds__(256) void reduce_k(
    const float* __restrict__ part, ll sOp, int S,
    const float* __restrict__ bias, const float* __restrict__ res,
    float* __restrict__ oF, ushort* __restrict__ oH, ushort* __restrict__ oL,
    int cols, int ldp, int ldo, float scale, ll sOut)
{
    int zb = blockIdx.z, r = blockIdx.y;
    int c = (blockIdx.x * 256 + threadIdx.x) * 4;
    if (c >= cols) return;
    const float* pb = part + ((ll)zb * S) * sOp + (ll)r * ldp + c;
    float4 v = *(const float4*)pb;
    for (int s = 1; s < S; ++s) {
        float4 t = *(const float4*)(pb + (ll)s * sOp);
        v.x += t.x; v.y += t.y; v.z += t.z; v.w += t.w;
    }
    v.x *= scale; v.y *= scale; v.z *= scale; v.w *= scale;
    if (bias) {
        float4 b4 = *(const float4*)(bias + c);
        v.x += b4.x; v.y += b4.y; v.z += b4.z; v.w += b4.w;
    }
    ll off = (ll)zb * sOut + (ll)r * ldo + c;
    if (SPLIT) {
        ushort4 h, l;
        split2(v.x, h.x, l.x); split2(v.y, h.y, l.y);
        split2(v.z, h.z, l.z); split2(v.w, h.w, l.w);
        *(ushort4*)(oH + off) = h;
        *(ushort4*)(oL + off) = l;
    } else {
        if (res) {
            float4 r4 = *(const float4*)(res + off);
            v.x += r4.x; v.y += r4.y; v.z += r4.z; v.w += r4.w;
        }
        *(float4*)(oF + off) = v;
    }
}

// ---------------------------------------------------------------------------
// LayerNorm -> split-bf16 planes. One block per row of 1024.
// ---------------------------------------------------------------------------
__global__ __launch_bounds__(256) void ln_split(
    const float* __restrict__ x, const float* __restrict__ gg,
    const float* __restrict__ bt, ushort* __restrict__ oH, ushort* __restrict__ oL)
{
    int row = blockIdx.x;
    int tid = threadIdx.x;
    const float4 v = *(const float4*)(x + (size_t)row * CC + tid * 4);
    float s  = v.x + v.y + v.z + v.w;
    float ss = v.x * v.x + v.y * v.y + v.z * v.z + v.w * v.w;
#pragma unroll
    for (int off = 32; off >= 1; off >>= 1) {
        s  += __shfl_xor(s, off);
        ss += __shfl_xor(ss, off);
    }
    __shared__ float rs[4], rss[4];
    int wave = tid >> 6;
    if ((tid & 63) == 0) { rs[wave] = s; rss[wave] = ss; }
    __syncthreads();
    float S  = rs[0] + rs[1] + rs[2] + rs[3];
    float SS = rss[0] + rss[1] + rss[2] + rss[3];
    float mu   = S * (1.0f / CC);
    float var  = SS * (1.0f / CC) - mu * mu;
    float rstd = rsqrtf(var + 1e-5f);
    int c = tid * 4;
    float4 g4 = *(const float4*)(gg + c);
    float4 b4 = *(const float4*)(bt + c);
    float r0 = (v.x - mu) * rstd * g4.x + b4.x;
    float r1 = (v.y - mu) * rstd * g4.y + b4.y;
    float r2 = (v.z - mu) * rstd * g4.z + b4.z;
    float r3 = (v.w - mu) * rstd * g4.w + b4.w;
    ushort4 h, l;
    split2(r0, h.x, l.x); split2(r1, h.y, l.y);
    split2(r2, h.z, l.z); split2(r3, h.w, l.w);
    *(ushort4*)(oH + (size_t)row * CC + c) = h;
    *(ushort4*)(oL + (size_t)row * CC + c) = l;
}

// ---------------------------------------------------------------------------
// Weight transpose + split: W [Kd][Nd] fp32 -> WH/WL [Nd][Kd] bf16
// ---------------------------------------------------------------------------
__global__ __launch_bounds__(256) void wsplit_T(
    const float* __restrict__ W, ushort* __restrict__ oH, ushort* __restrict__ oL,
    int Kd, int Nd)
{
    __shared__ float t[64][65];
    int n0 = blockIdx.x * 64, k0 = blockIdx.y * 64;
    int tid = threadIdx.x;
#pragma unroll
    for (int j = 0; j < 16; ++j) {
        int i = j * 256 + tid;
        int r = i >> 6, c = i & 63;
        t[r][c] = W[(size_t)(k0 + r) * Nd + n0 + c];
    }
    __syncthreads();
#pragma unroll
    for (int j = 0; j < 16; ++j) {
        int i = j * 256 + tid;
        int rn = i >> 6, ck = i & 63;
        float v = t[ck][rn];
        ushort h, l; split2(v, h, l);
        size_t off = (size_t)(n0 + rn) * Kd + k0 + ck;
        oH[off] = h; oL[off] = l;
    }
}

// elementwise fp32 -> split planes (img_emb)
__global__ __launch_bounds__(256) void split_rows(
    const float* __restrict__ x, ushort* __restrict__ oH, ushort* __restrict__ oL, int n4)
{
    int i = blockIdx.x * 256 + threadIdx.x;
    if (i >= n4) return;
    float4 v = ((const float4*)x)[i];
    ushort4 h, l;
    split2(v.x, h.x, l.x); split2(v.y, h.y, l.y);
    split2(v.z, h.z, l.z); split2(v.w, h.w, l.w);
    ((ushort4*)oH)[i] = h; ((ushort4*)oL)[i] = l;
}

// ---------------------------------------------------------------------------
// Self-attn V^T prep: qkvH [B*T][3072] cols 2048+h*64.. -> vT [(b*16+h)*64+d][T]
// ---------------------------------------------------------------------------
__global__ __launch_bounds__(256) void vt_self(
    const ushort* __restrict__ qkvH, ushort* __restrict__ vT)
{
    __shared__ ushort t[64][72];
    int bh = blockIdx.y, b = bh >> 4, h = bh & 15;
    int t0 = blockIdx.x * 64;
    int tid = threadIdx.x;
    int r = tid >> 2, c0 = (tid & 3) * 16;
    const ushort* src = qkvH + (size_t)(b * TT + t0 + r) * 3072 + 2048 + h * HD + c0;
    *(short8*)&t[r][c0]     = *(const short8*)(src);
    *(short8*)&t[r][c0 + 8] = *(const short8*)(src + 8);
    __syncthreads();
    ushort* dst = vT + ((size_t)bh * HD + r) * TT + t0 + c0;
#pragma unroll
    for (int i = 0; i < 16; ++i) dst[i] = t[c0 + i][r];
}

// ---------------------------------------------------------------------------
// MFMA flash causal self-attention (unchanged from round 3).
// ---------------------------------------------------------------------------
__global__ __launch_bounds__(256) void flash_mfma(
    const ushort* __restrict__ qkvH, const ushort* __restrict__ qkvL,
    const ushort* __restrict__ vT,
    ushort* __restrict__ oH, ushort* __restrict__ oL)
{
    __shared__ __align__(16) ushort Ks[64 * 72];
    __shared__ __align__(16) ushort Vs[64 * 72];
    __shared__ __align__(16) ushort PsH[64 * 72];
    __shared__ __align__(16) ushort PsL[64 * 72];

    int bh = blockIdx.y, b = bh >> 4, h = bh & 15;
    int qt = blockIdx.x;
    int tid = threadIdx.x;
    int w = tid >> 6, lane = tid & 63, g = lane >> 4, fr = lane & 15;

    short8 qh[2], ql[2];
    {
        size_t qoff = (size_t)(b * TT + qt * 64 + w * 16 + fr) * 3072 + h * HD + g * 8;
        qh[0] = *(const short8*)(qkvH + qoff);
        qh[1] = *(const short8*)(qkvH + qoff + 32);
        ql[0] = *(const short8*)(qkvL + qoff);
        ql[1] = *(const short8*)(qkvL + qoff + 32);
    }

    f32x4 o[4];
#pragma unroll
    for (int n = 0; n < 4; ++n) o[n] = (f32x4)0.0f;
    float mrow[4] = {-INFINITY, -INFINITY, -INFINITY, -INFINITY};
    float lrow[4] = {0.0f, 0.0f, 0.0f, 0.0f};

    int sr = tid >> 2, sc = (tid & 3) * 16;
    const ushort* kbase = qkvH + (size_t)(b * TT) * 3072 + 1024 + h * HD + sc;
    const ushort* vbase = vT + ((size_t)bh * HD + sr) * TT + sc;

    const float SC = 0.18033688011112042f;   // 0.125 * log2(e)

    for (int kt = 0; kt <= qt; ++kt) {
        __syncthreads();
        {
            const ushort* ksrc = kbase + (size_t)(kt * 64 + sr) * 3072;
            *(short8*)&Ks[sr * 72 + sc]     = *(const short8*)(ksrc);
            *(short8*)&Ks[sr * 72 + sc + 8] = *(const short8*)(ksrc + 8);
            const ushort* vsrc = vbase + kt * 64;
            *(short8*)&Vs[sr * 72 + sc]     = *(const short8*)(vsrc);
            *(short8*)&Vs[sr * 72 + sc + 8] = *(const short8*)(vsrc + 8);
        }
        __syncthreads();

        f32x4 s[4];
#pragma unroll
        for (int n = 0; n < 4; ++n) s[n] = (f32x4)0.0f;
#pragma unroll
        for (int n = 0; n < 4; ++n) {
#pragma unroll
            for (int c = 0; c < 2; ++c) {
                short8 kf = *(const short8*)&Ks[(n * 16 + fr) * 72 + c * 32 + g * 8];
                s[n] = __builtin_amdgcn_mfma_f32_16x16x32_bf16(qh[c], kf, s[n], 0, 0, 0);
                s[n] = __builtin_amdgcn_mfma_f32_16x16x32_bf16(ql[c], kf, s[n], 0, 0, 0);
            }
        }

        float pm[4] = {-INFINITY, -INFINITY, -INFINITY, -INFINITY};
        bool diag = (kt == qt);
#pragma unroll
        for (int n = 0; n < 4; ++n) {
#pragma unroll
            for (int e = 0; e < 4; ++e) {
                float sv = s[n][e] * SC;
                if (diag && (16 * n + fr) > (w * 16 + g * 4 + e)) sv = -INFINITY;
                s[n][e] = sv;
                pm[e] = fmaxf(pm[e], sv);
            }
        }
#pragma unroll
        for (int e = 0; e < 4; ++e) {
            pm[e] = fmaxf(pm[e], __shfl_xor(pm[e], 1));
            pm[e] = fmaxf(pm[e], __shfl_xor(pm[e], 2));
            pm[e] = fmaxf(pm[e], __shfl_xor(pm[e], 4));
            pm[e] = fmaxf(pm[e], __shfl_xor(pm[e], 8));
        }
        float alpha[4];
#pragma unroll
        for (int e = 0; e < 4; ++e) {
            float mn = fmaxf(mrow[e], pm[e]);
            alpha[e] = exp2f(mrow[e] - mn);
            mrow[e] = mn;
        }
        float ls[4] = {0.0f, 0.0f, 0.0f, 0.0f};
#pragma unroll
        for (int n = 0; n < 4; ++n)
#pragma unroll
            for (int e = 0; e < 4; ++e) {
                float p = exp2f(s[n][e] - mrow[e]);
                s[n][e] = p;
                ls[e] += p;
            }
#pragma unroll
        for (int e = 0; e < 4; ++e) {
            ls[e] += __shfl_xor(ls[e], 1);
            ls[e] += __shfl_xor(ls[e], 2);
            ls[e] += __shfl_xor(ls[e], 4);
            ls[e] += __shfl_xor(ls[e], 8);
            lrow[e] = lrow[e] * alpha[e] + ls[e];
        }

#pragma unroll
        for (int n = 0; n < 4; ++n)
#pragma unroll
            for (int e = 0; e < 4; ++e) {
                ushort ph, pl;
                split2(s[n][e], ph, pl);
                int idx = (w * 16 + g * 4 + e) * 72 + n * 16 + fr;
                PsH[idx] = ph; PsL[idx] = pl;
            }

#pragma unroll
        for (int n = 0; n < 4; ++n)
#pragma unroll
            for (int e = 0; e < 4; ++e) o[n][e] *= alpha[e];

        short8 paH[2], paL[2];
#pragma unroll
        for (int c = 0; c < 2; ++c) {
            paH[c] = *(const short8*)&PsH[(w * 16 + fr) * 72 + c * 32 + g * 8];
            paL[c] = *(const short8*)&PsL[(w * 16 + fr) * 72 + c * 32 + g * 8];
        }
#pragma unroll
        for (int n = 0; n < 4; ++n) {
#pragma unroll
            for (int c = 0; c < 2; ++c) {
                short8 vf = *(const short8*)&Vs[(n * 16 + fr) * 72 + c * 32 + g * 8];
                o[n] = __builtin_amdgcn_mfma_f32_16x16x32_bf16(paH[c], vf, o[n], 0, 0, 0);
                o[n] = __builtin_amdgcn_mfma_f32_16x16x32_bf16(paL[c], vf, o[n], 0, 0, 0);
            }
        }
    }

    float inv[4];
#pragma unroll
    for (int e = 0; e < 4; ++e) inv[e] = 1.0f / lrow[e];
#pragma unroll
    for (int n = 0; n < 4; ++n)
#pragma unroll
        for (int e = 0; e < 4; ++e) {
            float v = o[n][e] * inv[e];
            ushort hh, lo;
            split2(v, hh, lo);
            size_t off = (size_t)(b * TT + qt * 64 + w * 16 + g * 4 + e) * CC
                       + h * HD + n * 16 + fr;
            oH[off] = hh; oL[off] = lo;
        }
}

// ---------------------------------------------------------------------------
// Cross-attn v^T: kv split planes [1028][2048] cols 1024.. -> vT [4][1024][288]
// ---------------------------------------------------------------------------
__global__ __launch_bounds__(256) void vtrans(
    const ushort* __restrict__ kvH, const ushort* __restrict__ kvL,
    ushort* __restrict__ vTH, ushort* __restrict__ vTL)
{
    __shared__ ushort tH[32][34], tL[32][34];
    int z = blockIdx.z;
    int kk0 = blockIdx.x * 32, c0 = blockIdx.y * 32;
    int tid = threadIdx.x;
    int r = tid >> 5, c = tid & 31;
#pragma unroll
    for (int p = 0; p < 4; ++p) {
        int kk = kk0 + r + 8 * p;
        bool ok = kk < TT2;
        size_t src = (size_t)(z * TT2 + (ok ? kk : 0)) * 2048 + CC + c0 + c;
        tH[r + 8 * p][c] = ok ? kvH[src] : (ushort)0;
        tL[r + 8 * p][c] = ok ? kvL[src] : (ushort)0;
    }
    __syncthreads();
#pragma unroll
    for (int p = 0; p < 4; ++p) {
        int cc = c0 + r + 8 * p;
        size_t dst = ((size_t)z * CC + cc) * 288 + kk0 + c;
        vTH[dst] = tH[c][r + 8 * p];
        vTL[dst] = tL[c][r + 8 * p];
    }
}

// ---------------------------------------------------------------------------
// Row softmax over length-257 fp32 rows (ld 288) -> split planes ld 288
// ---------------------------------------------------------------------------
__global__ __launch_bounds__(256) void softmax_split(
    const float* __restrict__ att, ushort* __restrict__ oH, ushort* __restrict__ oL)
{
    int row = blockIdx.x;
    const float* p = att + (size_t)row * 288;
    int tid = threadIdx.x;
    float v0 = p[tid];
    float v1 = (tid == 0) ? p[256] : -INFINITY;
    float m = fmaxf(v0, v1);
#pragma unroll
    for (int off = 32; off >= 1; off >>= 1) m = fmaxf(m, __shfl_xor(m, off));
    __shared__ float red[8];
    int wave = tid >> 6;
    if ((tid & 63) == 0) red[wave] = m;
    __syncthreads();
    m = fmaxf(fmaxf(red[0], red[1]), fmaxf(red[2], red[3]));
    float e0 = expf(v0 - m);
    float e1 = (tid == 0) ? expf(v1 - m) : 0.0f;
    float s = e0 + e1;
#pragma unroll
    for (int off = 32; off >= 1; off >>= 1) s += __shfl_xor(s, off);
    if ((tid & 63) == 0) red[4 + wave] = s;
    __syncthreads();
    s = red[4] + red[5] + red[6] + red[7];
    float inv = 1.0f / s;
    size_t base = (size_t)row * 288;
    ushort h, l;
    split2(e0 * inv, h, l);
    oH[base + tid] = h; oL[base + tid] = l;
    if (tid < 32) {
        float v = (tid == 0) ? e1 * inv : 0.0f;
        split2(v, h, l);
        oH[base + 256 + tid] = h; oL[base + 256 + tid] = l;
    }
}

__global__ __launch_bounds__(256) void copy4_kernel(
    const float4* __restrict__ src, float4* __restrict__ dst, int n4)
{
    int i = blockIdx.x * blockDim.x + threadIdx.x;
    if (i < n4) dst[i] = src[i];
}

extern "C" void kernel_launch(void* const* d_in, const int* in_sizes, int n_in,
                              void* d_out, int out_size, void* d_ws, size_t ws_size,
                              hipStream_t stream)
{
    const float* text_emb    = (const float*)d_in[0];
    const float* img_emb     = (const float*)d_in[1];
    const float* ln1_g       = (const float*)d_in[2];
    const float* ln1_b       = (const float*)d_in[3];
    const float* ln2_g       = (const float*)d_in[4];
    const float* ln2_b       = (const float*)d_in[5];
    const float* ln3_g       = (const float*)d_in[6];
    const float* ln3_b       = (const float*)d_in[7];
    const float* qkv_w       = (const float*)d_in[8];
    const float* qkv_b       = (const float*)d_in[9];
    const float* attn_proj_w = (const float*)d_in[10];
    const float* attn_proj_b = (const float*)d_in[11];
    const float* ca_q_w      = (const float*)d_in[12];
    const float* ca_q_b      = (const float*)d_in[13];
    const float* ca_kv_w     = (const float*)d_in[14];
    const float* ca_kv_b     = (const float*)d_in[15];
    const float* ca_proj_w   = (const float*)d_in[16];
    const float* ca_proj_b   = (const float*)d_in[17];
    const float* mlp_fc_w    = (const float*)d_in[18];
    const float* mlp_fc_b    = (const float*)d_in[19];
    const float* mlp_proj_w  = (const float*)d_in[20];
    const float* mlp_proj_b  = (const float*)d_in[21];

    const int M1 = BB * TT;   // 4096
    const int Mkv = BB * TT2; // 1028

    // ---- workspace arena (96 MB, time-multiplexed `big` region) ----
    char* base = (char*)d_ws;
    ushort* wH   = (ushort*)base;                        // 8 MB weight planes
    ushort* wL   = (ushort*)(base + (8u << 20));
    char* big    = base + (16u << 20);                   // 64 MB multi-use
    // steps 2-3:
    ushort* qkvH = (ushort*)big;                         // 24 MB
    ushort* qkvL = (ushort*)(big + (24u << 20));         // 24 MB
    ushort* vTs  = (ushort*)(big + (48u << 20));         // 8 MB
    // step 4:
    float*  P4   = (float*)big;                          // 32 MB (S=2)
    // steps 6-9:
    ushort* qH   = (ushort*)big;                         // 8 MB
    ushort* qL   = (ushort*)(big + (8u  << 20));
    float*  P6   = (float*)(big + (16u << 20));          // 32 MB
    ushort* kvH  = (ushort*)(big + (16u << 20));         // 5 MB slot
    ushort* kvL  = (ushort*)(big + (21u << 20));
    float*  P7   = (float*)(big + (32u << 20));          // 17 MB
    ushort* imgH = (ushort*)(big + (50u << 20));         // 3 MB slot
    ushort* imgL = (ushort*)(big + (53u << 20));
    ushort* vTH  = (ushort*)(big + (26u << 20));         // 3 MB slot
    ushort* vTL  = (ushort*)(big + (29u << 20));
    float*  attF = (float*) (big + (32u << 20));         // 5 MB (ld 288)
    float*  P9   = (float*)(big + (37u << 20));          // 19 MB (S=4)
    // steps 10-11:
    ushort* attH = (ushort*)big;                         // 2.4 MB
    ushort* attL = (ushort*)(big + (3u  << 20));
    float*  P11  = (float*)(big + (32u << 20));          // 32 MB (S=2)
    // step 12:
    float*  P12  = (float*)big;                          // 32 MB
    // steps 14-15:
    ushort* hH   = (ushort*)big;                         // 32 MB (hi only)
    float*  P15  = (float*)(big + (32u << 20));          // 32 MB
    char* actA   = base + (80u << 20);
    ushort* aH   = (ushort*)actA;                        // 8 MB
    ushort* aL   = (ushort*)(actA + (8u << 20));

    float* out_x   = (float*)d_out;
    float* out_img = out_x + (size_t)M1 * CC;

    // 1. ln1(text) -> aH/aL
    ln_split<<<dim3(M1), 256, 0, stream>>>(text_emb, ln1_g, ln1_b, aH, aL);

    // 2. qkv = ln1 @ qkv_w + b -> split planes (grid 768 = 3/CU, no split-K)
    wsplit_T<<<dim3(3 * CC / 64, CC / 64), 256, 0, stream>>>(qkv_w, wH, wL, CC, 3 * CC);
    gemm_sp<1, 2><<<dim3(24, 32, 1), 256, 0, stream>>>(
        aH, aL, CC, wH, wL, CC, qkv_b, nullptr, qkvH, qkvL,
        M1, 3 * CC, CC, 3 * CC, 0, 0, 0, 1);

    // 2b. V^T prep for self-attn
    vt_self<<<dim3(TT / 64, BB * NH), 256, 0, stream>>>(qkvH, vTs);

    // 3. MFMA flash attention -> aH/aL
    flash_mfma<<<dim3(TT / 64, BB * NH), 256, 0, stream>>>(qkvH, qkvL, vTs, aH, aL);

    // 4. x = text + attn @ proj_w + b   (split-K=2)
    wsplit_T<<<dim3(CC / 64, CC / 64), 256, 0, stream>>>(attn_proj_w, wH, wL, CC, CC);
    gemm_sp<3, 2><<<dim3(8, 32, 2), 256, 0, stream>>>(
        aH, aL, CC, wH, wL, CC, nullptr, P4, nullptr, nullptr,
        M1, CC, CC, CC, 0, 0, (ll)M1 * CC, 2);
    reduce_k<false><<<dim3(1, M1, 1), 256, 0, stream>>>(
        P4, (ll)M1 * CC, 2, attn_proj_b, text_emb, out_x, nullptr, nullptr,
        CC, CC, CC, 1.0f, 0);

    // 5. ln3(x) -> aH/aL
    ln_split<<<dim3(M1), 256, 0, stream>>>(out_x, ln3_g, ln3_b, aH, aL);

    // 6. q = ln3 @ ca_q_w + b -> split qH/qL   (split-K=2)
    wsplit_T<<<dim3(CC / 64, CC / 64), 256, 0, stream>>>(ca_q_w, wH, wL, CC, CC);
    gemm_sp<3, 2><<<dim3(8, 32, 2), 256, 0, stream>>>(
        aH, aL, CC, wH, wL, CC, nullptr, P6, nullptr, nullptr,
        M1, CC, CC, CC, 0, 0, (ll)M1 * CC, 2);
    reduce_k<true><<<dim3(1, M1, 1), 256, 0, stream>>>(
        P6, (ll)M1 * CC, 2, ca_q_b, nullptr, nullptr, qH, qL,
        CC, CC, CC, 1.0f, 0);

    // 7. kv = img @ ca_kv_w + b -> split kvH/kvL [1028][2048]  (split-K=2)
    split_rows<<<dim3(Mkv), 256, 0, stream>>>(img_emb, imgH, imgL, Mkv * CC / 4);
    wsplit_T<<<dim3(2 * CC / 64, CC / 64), 256, 0, stream>>>(ca_kv_w, wH, wL, CC, 2 * CC);
    gemm_sp<3, 2><<<dim3(16, 9, 2), 256, 0, stream>>>(
        imgH, imgL, CC, wH, wL, CC, nullptr, P7, nullptr, nullptr,
        Mkv, 2 * CC, CC, 2 * CC, 0, 0, (ll)Mkv * 2 * CC, 2);
    reduce_k<true><<<dim3(2, Mkv, 1), 256, 0, stream>>>(
        P7, (ll)Mkv * 2 * CC, 2, ca_kv_b, nullptr, nullptr, kvH, kvL,
        2 * CC, 2 * CC, 2 * CC, 1.0f, 0);

    // 8. cross v^T -> vTH/vTL [4][1024][288]
    vtrans<<<dim3(9, 32, BB), 256, 0, stream>>>(kvH, kvL, vTH, vTL);

    // 9. att = (q @ k^T)/32 (batched, split-K=4, N padded to 288) -> attF ld 288
    gemm_sp<3, 2><<<dim3(3, 8, BB * 4), 256, 0, stream>>>(
        qH, qL, CC, kvH, kvL, 2 * CC, nullptr, P9, nullptr, nullptr,
        TT, 288, CC, 288, (ll)TT * CC, (ll)TT2 * 2 * CC, (ll)TT * 288, 4);
    reduce_k<false><<<dim3(1, TT, BB), 256, 0, stream>>>(
        P9, (ll)TT * 288, 4, nullptr, nullptr, attF, nullptr, nullptr,
        288, 288, 288, 0.03125f, (ll)TT * 288);

    // 10. softmax -> split attH/attL ld 288
    softmax_split<<<dim3(BB * TT), 256, 0, stream>>>(attF, attH, attL);

    // 11. caout = att @ v (batched, K=288, split-K=2) -> split aH/aL
    gemm_sp<3, 2><<<dim3(8, 8, BB * 2), 256, 0, stream>>>(
        attH, attL, 288, vTH, vTL, 288, nullptr, P11, nullptr, nullptr,
        TT, CC, 288, CC, (ll)TT * 288, (ll)CC * 288, (ll)TT * CC, 2);
    reduce_k<true><<<dim3(1, TT, BB), 256, 0, stream>>>(
        P11, (ll)TT * CC, 2, nullptr, nullptr, nullptr, aH, aL,
        CC, CC, CC, 1.0f, (ll)TT * CC);

    // 12. x += caout @ ca_proj_w + b   (split-K=2)
    wsplit_T<<<dim3(CC / 64, CC / 64), 256, 0, stream>>>(ca_proj_w, wH, wL, CC, CC);
    gemm_sp<3, 2><<<dim3(8, 32, 2), 256, 0, stream>>>(
        aH, aL, CC, wH, wL, CC, nullptr, P12, nullptr, nullptr,
        M1, CC, CC, CC, 0, 0, (ll)M1 * CC, 2);
    reduce_k<false><<<dim3(1, M1, 1), 256, 0, stream>>>(
        P12, (ll)M1 * CC, 2, ca_proj_b, out_x, out_x, nullptr, nullptr,
        CC, CC, CC, 1.0f, 0);

    // 13. ln2(x) -> aH/aL
    ln_split<<<dim3(M1), 256, 0, stream>>>(out_x, ln2_g, ln2_b, aH, aL);

    // 14. h = gelu(ln2 @ fc_w + b) -> hH only (hi plane)  [grid 1024 = 4/CU]
    wsplit_T<<<dim3(4 * CC / 64, CC / 64), 256, 0, stream>>>(mlp_fc_w, wH, wL, CC, 4 * CC);
    gemm_sp<2, 2><<<dim3(32, 32, 1), 256, 0, stream>>>(
        aH, aL, CC, wH, wL, CC, mlp_fc_b, nullptr, hH, nullptr,
        M1, 4 * CC, CC, 4 * CC, 0, 0, 0, 1);

    // 15. x += h @ mlp_proj_w + b   (A hi-only 2-pass, split-K=2)
    wsplit_T<<<dim3(CC / 64, 4 * CC / 64), 256, 0, stream>>>(mlp_proj_w, wH, wL, 4 * CC, CC);
    gemm_sp<3, 1><<<dim3(8, 32, 2), 256, 0, stream>>>(
        hH, nullptr, 4 * CC, wH, wL, 4 * CC, nullptr, P15, nullptr, nullptr,
        M1, CC, 4 * CC, CC, 0, 0, (ll)M1 * CC, 2);
    reduce_k<false><<<dim3(1, M1, 1), 256, 0, stream>>>(
        P15, (ll)M1 * CC, 2, mlp_proj_b, out_x, out_x, nullptr, nullptr,
        CC, CC, CC, 1.0f, 0);

    // 16. out_img = img_emb
    {
        int n4 = (BB * TT2 * CC) / 4;
        copy4_kernel<<<dim3((n4 + 255) / 256), 256, 0, stream>>>(
            (const float4*)img_emb, (float4*)out_img, n4);
    }
}